// Round 9
// baseline (220.164 us; speedup 1.0000x reference)
//
#include <hip/hip_runtime.h>

#define N_NODES   50000
#define N_EDGES   800000
#define NODE_DIM  128
#define HIDDEN    256
#define LATENT    128
#define COND      5

#define SCAN_BLOCKS ((N_NODES + 255) / 256)   // 196
#define NB          196                        // buckets: dst>>8 (256-node ranges)
#define P1_CHUNK    4096
#define P1_GRID     ((N_EDGES + P1_CHUNK - 1) / P1_CHUNK)  // 196

typedef unsigned int uint;
typedef unsigned short ushort;
typedef unsigned char uchar;

typedef __attribute__((ext_vector_type(8))) short bf16x8;
typedef __attribute__((ext_vector_type(4))) float f32x4;

static __device__ __forceinline__ ushort f32_to_bf16(float f) {
    union { float f; uint u; } v; v.f = f;
    uint r = v.u + 0x7FFF + ((v.u >> 16) & 1);   // RNE
    return (ushort)(r >> 16);
}
static __device__ __forceinline__ uint pack_bf16(float lo, float hi) {
    return (uint)f32_to_bf16(lo) | ((uint)f32_to_bf16(hi) << 16);
}

// ---------------- fp8 e4m3 helpers (HW cvt with software fallback) ----------------

#if __has_builtin(__builtin_amdgcn_cvt_pk_f32_fp8) && __has_builtin(__builtin_amdgcn_cvt_pk_fp8_f32)
#define HW_FP8 1
#endif

#ifndef HW_FP8
static __device__ __forceinline__ float dec1_fp8(uint b) {
    uint sgn = b & 0x80, mag = b & 0x7f;
    float v;
    if (mag >= 8) {
        union { uint u; float f; } t;
        t.u = (((mag >> 3) + 120) << 23) | ((mag & 7) << 20);
        v = t.f;
    } else {
        v = (float)mag * 0.001953125f;   // 2^-9
    }
    return sgn ? -v : v;
}
static __device__ __forceinline__ uchar enc1_fp8(float f) {
    float a = fabsf(f);
    uint s = (f < 0.f) ? 0x80u : 0u;
    if (!(a >= 0.015625f)) {
        int q = (int)(a * 512.f + 0.5f);
        if (q > 7) q = 7;
        return (uchar)(s | (uint)q);
    }
    if (a >= 448.f) return (uchar)(s | 0x7E);
    union { float f; uint u; } t; t.f = a;
    uint e = (t.u >> 23) - 120;
    uint m = (t.u >> 20) & 7;
    uint rem = t.u & 0xFFFFF;
    uint v = (e << 3) | m;
    if (rem > 0x80000 || (rem == 0x80000 && (v & 1))) v++;
    if (v > 0x7E) v = 0x7E;
    return (uchar)(s | v);
}
#endif

static __device__ __forceinline__ void dec4_add(uint u, float* acc) {
#ifdef HW_FP8
    auto lo = __builtin_amdgcn_cvt_pk_f32_fp8((int)u, false);
    auto hi = __builtin_amdgcn_cvt_pk_f32_fp8((int)u, true);
    acc[0] += lo[0]; acc[1] += lo[1]; acc[2] += hi[0]; acc[3] += hi[1];
#else
    acc[0] += dec1_fp8(u & 0xff);
    acc[1] += dec1_fp8((u >> 8) & 0xff);
    acc[2] += dec1_fp8((u >> 16) & 0xff);
    acc[3] += dec1_fp8(u >> 24);
#endif
}
static __device__ __forceinline__ void dec2_add(uint u, float* acc) {
#ifdef HW_FP8
    auto lo = __builtin_amdgcn_cvt_pk_f32_fp8((int)u, false);
    acc[0] += lo[0]; acc[1] += lo[1];
#else
    acc[0] += dec1_fp8(u & 0xff);
    acc[1] += dec1_fp8((u >> 8) & 0xff);
#endif
}
static __device__ __forceinline__ uint enc2_fp8(float a, float b) {
#ifdef HW_FP8
    return (uint)__builtin_amdgcn_cvt_pk_fp8_f32(a, b, 0, false) & 0xFFFFu;
#else
    return (uint)enc1_fp8(a) | ((uint)enc1_fp8(b) << 8);
#endif
}
static __device__ __forceinline__ uchar enc1(float v) {
#ifdef HW_FP8
    return (uchar)(__builtin_amdgcn_cvt_pk_fp8_f32(v, v, 0, false) & 0xff);
#else
    return enc1_fp8(v);
#endif
}

// ---------------- prep: nf -> fp8, W transpose (bf16), deg/pooled zero ----------------

#define NF4   (N_NODES * NODE_DIM / 4)            // 1,600,000
#define PREP1 (NF4 + NODE_DIM * HIDDEN)           // + 32768
#define PREP2 (PREP1 + HIDDEN * HIDDEN)           // + 65536
#define PREP3 (PREP2 + N_NODES)                   // + 50000 (deg zero)
#define PREP4 (PREP3 + HIDDEN)                    // + 256 (pooled zero)

__global__ void prep_kernel(const float* __restrict__ nf,
                            const float* __restrict__ W1, const float* __restrict__ W2,
                            uchar* __restrict__ nf_fp8,
                            ushort* __restrict__ Wt1, ushort* __restrict__ Wt2,
                            int* __restrict__ deg, float* __restrict__ pooled) {
    int id = blockIdx.x * blockDim.x + threadIdx.x;
    if (id < NF4) {
        float4 v = reinterpret_cast<const float4*>(nf)[id];
        uint w = enc2_fp8(v.x, v.y) | (enc2_fp8(v.z, v.w) << 16);
        reinterpret_cast<uint*>(nf_fp8)[id] = w;
    } else if (id < PREP1) {
        int i = id - NF4;
        int k = i >> 8, c = i & 255;
        Wt1[c * NODE_DIM + k] = f32_to_bf16(W1[i]);
    } else if (id < PREP2) {
        int i = id - PREP1;
        int k = i >> 8, c = i & 255;
        Wt2[c * HIDDEN + k] = f32_to_bf16(W2[i]);
    } else if (id < PREP3) {
        deg[id - PREP2] = 0;
    } else if (id < PREP4) {
        pooled[id - PREP3] = 0.f;
    }
}

// ---------------- CSR build ----------------

__global__ void hist_kernel(const int* __restrict__ dst, int* __restrict__ deg) {
    int e = blockIdx.x * blockDim.x + threadIdx.x;
    if (e < N_EDGES) atomicAdd(&deg[dst[e]], 1);
}

__global__ void scan_a_kernel(const int* __restrict__ deg, int* __restrict__ incl,
                              int* __restrict__ blocksums) {
    int i = blockIdx.x * 256 + threadIdx.x;
    int lane = threadIdx.x & 63;
    int w    = threadIdx.x >> 6;
    int v = (i < N_NODES) ? deg[i] : 0;
    int s = v;
#pragma unroll
    for (int d = 1; d < 64; d <<= 1) {
        int t = __shfl_up(s, d);
        if (lane >= d) s += t;
    }
    __shared__ int wsum[4];
    if (lane == 63) wsum[w] = s;
    __syncthreads();
    int add = 0;
    for (int k = 0; k < w; ++k) add += wsum[k];
    s += add;
    if (i < N_NODES) incl[i] = s;
    if (threadIdx.x == 255) blocksums[blockIdx.x] = s;
}

__global__ void scan_c_kernel(const int* __restrict__ deg, const int* __restrict__ incl,
                              const int* __restrict__ blocksums,
                              int* __restrict__ offsets, int* __restrict__ bcursor) {
    __shared__ int s[256];
    int t = threadIdx.x;
    s[t] = (t < SCAN_BLOCKS) ? blocksums[t] : 0;
    __syncthreads();
    for (int off = 1; off < 256; off <<= 1) {
        int v = (t >= off) ? s[t - off] : 0;
        __syncthreads();
        s[t] += v;
        __syncthreads();
    }
    int bo = (blockIdx.x == 0) ? 0 : s[blockIdx.x - 1];
    int i = blockIdx.x * 256 + t;
    if (i < N_NODES) {
        int inc = incl[i];
        int off = bo + inc - deg[i];
        offsets[i] = off;
        if ((i & 255) == 0) bcursor[i >> 8] = off;
        if (i == N_NODES - 1) offsets[N_NODES] = bo + inc;
    }
}

// ---------------- pass 1: bucket multi-split ----------------

__global__ __launch_bounds__(256) void bucket_kernel(const int* __restrict__ src,
                                                     const int* __restrict__ dst,
                                                     int* __restrict__ bcursor,
                                                     uint* __restrict__ pair_buf) {
    __shared__ int cnt[NB];
    __shared__ int gbase[NB];
    const int t = threadIdx.x;
    for (int i = t; i < NB; i += 256) cnt[i] = 0;
    __syncthreads();

    const int base = blockIdx.x * P1_CHUNK;
    uint pk[16];
    int  bk[16], lr[16];
    bool ok[16];
#pragma unroll
    for (int i = 0; i < 16; ++i) {
        int e = base + i * 256 + t;
        ok[i] = e < N_EDGES;
        if (ok[i]) {
            int s = src[e], d = dst[e];
            pk[i] = (uint)s | ((uint)d << 16);
            bk[i] = d >> 8;
        }
    }
#pragma unroll
    for (int i = 0; i < 16; ++i)
        if (ok[i]) lr[i] = atomicAdd(&cnt[bk[i]], 1);
    __syncthreads();
    if (t < NB) {
        int c = cnt[t];
        gbase[t] = (c > 0) ? atomicAdd(&bcursor[t], c) : 0;
    }
    __syncthreads();
#pragma unroll
    for (int i = 0; i < 16; ++i)
        if (ok[i]) pair_buf[gbase[bk[i]] + lr[i]] = pk[i];
}

// ---------------- pass 2: block-local CSR scatter ----------------

__global__ __launch_bounds__(256) void csr_kernel(const uint* __restrict__ pair_buf,
                                                  const int* __restrict__ offsets,
                                                  ushort* __restrict__ csr) {
    __shared__ int loff[257];
    __shared__ int lcur[256];
    const int b  = blockIdx.x;
    const int t  = threadIdx.x;
    const int n0 = b << 8;
    int node = n0 + t;
    loff[t] = offsets[node < N_NODES ? node : N_NODES];
    if (t == 0) {
        int ne = n0 + 256;
        loff[256] = offsets[ne < N_NODES ? ne : N_NODES];
    }
    lcur[t] = 0;
    __syncthreads();
    const int e0 = loff[0], e1 = loff[256];
    for (int j = e0 + t; j < e1; j += 256) {
        uint p = pair_buf[j];
        int dl = (int)(p >> 16) - n0;
        int r = atomicAdd(&lcur[dl], 1);
        csr[loff[dl] + r] = (ushort)(p & 0xFFFFu);
    }
}

// ---------------- aggregation: wave per node, fp8 gather, 16-deep load pipeline ----------------

template <int D>
__global__ __launch_bounds__(256) void agg_kernel(const uchar* __restrict__ x,
                                                  const int* __restrict__ offsets,
                                                  const ushort* __restrict__ csr,
                                                  ushort* __restrict__ out) {
    constexpr int BPL = D / 64;   // bytes per lane: 2 or 4
    int node = (blockIdx.x * blockDim.x + threadIdx.x) >> 6;
    int lane = threadIdx.x & 63;
    if (node >= N_NODES) return;
    int j0 = __builtin_amdgcn_readfirstlane(offsets[node]);
    int j1 = __builtin_amdgcn_readfirstlane(offsets[node + 1]);

    float acc[BPL];
#pragma unroll
    for (int i = 0; i < BPL; ++i) acc[i] = 0.f;

    const uchar* base = x + lane * BPL;
    const int il = lane & 15;

    int idxv = (j0 + il < j1) ? (int)csr[j0 + il] : 0;

    for (int jb = j0; jb < j1; jb += 16) {
        int idxn = (jb + 16 + il < j1) ? (int)csr[jb + 16 + il] : 0;
        int n = j1 - jb; n = (n > 16) ? 16 : n;
        uint u[16];
        if (n == 16) {
#pragma unroll
            for (int i = 0; i < 16; ++i) {
                int s = __shfl(idxv, i);
                if constexpr (BPL == 4)
                    u[i] = *reinterpret_cast<const uint*>(base + (size_t)s * D);
                else
                    u[i] = *reinterpret_cast<const ushort*>(base + (size_t)s * D);
            }
#pragma unroll
            for (int i = 0; i < 16; ++i) {
                if constexpr (BPL == 4) dec4_add(u[i], acc); else dec2_add(u[i], acc);
            }
        } else {
#pragma unroll
            for (int i = 0; i < 16; ++i) {
                if (i < n) {
                    int s = __shfl(idxv, i);
                    if constexpr (BPL == 4)
                        u[i] = *reinterpret_cast<const uint*>(base + (size_t)s * D);
                    else
                        u[i] = *reinterpret_cast<const ushort*>(base + (size_t)s * D);
                }
            }
#pragma unroll
            for (int i = 0; i < 16; ++i) {
                if (i < n) {
                    if constexpr (BPL == 4) dec4_add(u[i], acc); else dec2_add(u[i], acc);
                }
            }
        }
        idxv = idxn;
    }

    if constexpr (BPL == 4) {
        uint2 o;
        o.x = pack_bf16(acc[0], acc[1]);
        o.y = pack_bf16(acc[2], acc[3]);
        *reinterpret_cast<uint2*>(out + (size_t)node * D + lane * 4) = o;
    } else {
        *reinterpret_cast<uint*>(out + (size_t)node * D + lane * 2) = pack_bf16(acc[0], acc[1]);
    }
}

// ---------------- MFMA GEMM v2: 32 rows/block, register double-buffered k-loop ----------------
// wave = 32 rows x 64 cols (2x4 fragments); 4 waves = 256 cols; grid = N/32 = 1563.
// POOL=false: store fp8 x1. POOL=true: column-sum relu into pooled.

template <int K, bool POOL>
__global__ __launch_bounds__(256) void gemm_kernel(const ushort* __restrict__ A,
                                                   const ushort* __restrict__ Wt,
                                                   const float* __restrict__ bias,
                                                   uchar* __restrict__ Xout,
                                                   float* __restrict__ pooled) {
    const int lane = threadIdx.x & 63;
    const int wv   = threadIdx.x >> 6;
    const int row0 = blockIdx.x * 32;
    const int col0 = wv * 64;
    const int fr   = lane & 15;
    const int kg   = (lane >> 4) * 8;

    const bf16x8 zero8 = {0, 0, 0, 0, 0, 0, 0, 0};
    f32x4 acc[2][4];
#pragma unroll
    for (int rt = 0; rt < 2; ++rt)
#pragma unroll
        for (int ct = 0; ct < 4; ++ct)
            acc[rt][ct] = (f32x4){0.f, 0.f, 0.f, 0.f};

    const ushort* Arow0 = A + (size_t)(row0 + fr) * K + kg;          // rt=0 row
    const ushort* Arow1 = A + (size_t)(row0 + 16 + fr) * K + kg;     // rt=1 row
    const bool g0 = (row0 + fr) < N_NODES;
    const bool g1 = (row0 + 16 + fr) < N_NODES;
    const ushort* Wrow[4];
#pragma unroll
    for (int ct = 0; ct < 4; ++ct)
        Wrow[ct] = Wt + (size_t)(col0 + ct * 16 + fr) * K + kg;

#define LOADA(dst0, dst1, k0)                                                     \
    dst0 = g0 ? *reinterpret_cast<const bf16x8*>(Arow0 + (k0)) : zero8;           \
    dst1 = g1 ? *reinterpret_cast<const bf16x8*>(Arow1 + (k0)) : zero8;
#define LOADB(bv, k0)                                                             \
    _Pragma("unroll")                                                             \
    for (int ct = 0; ct < 4; ++ct)                                                \
        bv[ct] = *reinterpret_cast<const bf16x8*>(Wrow[ct] + (k0));
#define MFMA8(a0, a1, bv)                                                         \
    _Pragma("unroll")                                                             \
    for (int ct = 0; ct < 4; ++ct) {                                              \
        acc[0][ct] = __builtin_amdgcn_mfma_f32_16x16x32_bf16(a0, bv[ct], acc[0][ct], 0, 0, 0); \
        acc[1][ct] = __builtin_amdgcn_mfma_f32_16x16x32_bf16(a1, bv[ct], acc[1][ct], 0, 0, 0); \
    }

    bf16x8 aA0, aA1, bA[4], aB0, aB1, bB[4];
    LOADA(aA0, aA1, 0)
    LOADB(bA, 0)
#pragma unroll
    for (int k0 = 0; k0 < K; k0 += 64) {
        if (k0 + 32 < K) { LOADA(aB0, aB1, k0 + 32) LOADB(bB, k0 + 32) }
        MFMA8(aA0, aA1, bA)
        if (k0 + 64 < K) { LOADA(aA0, aA1, k0 + 64) LOADB(bA, k0 + 64) }
        if (k0 + 32 < K) { MFMA8(aB0, aB1, bB) }
    }
#undef LOADA
#undef LOADB
#undef MFMA8

    float bcol[4];
#pragma unroll
    for (int ct = 0; ct < 4; ++ct) bcol[ct] = bias[col0 + ct * 16 + fr];
    const int mrow = (lane >> 4) * 4;

    if constexpr (POOL) {
        float cs[4] = {0.f, 0.f, 0.f, 0.f};
#pragma unroll
        for (int rt = 0; rt < 2; ++rt) {
#pragma unroll
            for (int e = 0; e < 4; ++e) {
                int m = row0 + rt * 16 + mrow + e;
                if (m < N_NODES) {
#pragma unroll
                    for (int ct = 0; ct < 4; ++ct)
                        cs[ct] += fmaxf(acc[rt][ct][e] + bcol[ct], 0.f);
                }
            }
        }
#pragma unroll
        for (int ct = 0; ct < 4; ++ct) {
            cs[ct] += __shfl_xor(cs[ct], 16);
            cs[ct] += __shfl_xor(cs[ct], 32);
        }
        if (lane < 16) {
#pragma unroll
            for (int ct = 0; ct < 4; ++ct)
                atomicAdd(&pooled[col0 + ct * 16 + lane], cs[ct]);
        }
    } else {
#pragma unroll
        for (int rt = 0; rt < 2; ++rt) {
#pragma unroll
            for (int e = 0; e < 4; ++e) {
                int m = row0 + rt * 16 + mrow + e;
                if (m < N_NODES) {
#pragma unroll
                    for (int ct = 0; ct < 4; ++ct) {
                        float v = fmaxf(acc[rt][ct][e] + bcol[ct], 0.f);
                        Xout[(size_t)m * HIDDEN + col0 + ct * 16 + fr] = enc1(v);
                    }
                }
            }
        }
    }
}

// ---------------- head MLP ----------------

__global__ void head_kernel(const float* __restrict__ pooled_sum, const float* __restrict__ cond,
                            const float* __restrict__ Wfc, const float* __restrict__ bfc,
                            const float* __restrict__ Wmean, const float* __restrict__ bmean,
                            const float* __restrict__ Wlogvar, const float* __restrict__ blogvar,
                            float* __restrict__ out) {
    __shared__ float v[HIDDEN + COND];
    __shared__ float h[LATENT];
    int t = threadIdx.x;
    if (t < HIDDEN) v[t] = pooled_sum[t] * (1.0f / N_NODES);
    if (t < COND) v[HIDDEN + t] = cond[t];
    __syncthreads();
    if (t < LATENT) {
        float s = bfc[t];
        for (int k = 0; k < HIDDEN + COND; ++k) s += v[k] * Wfc[k * LATENT + t];
        h[t] = fmaxf(s, 0.f);
    }
    __syncthreads();
    if (t < LATENT) {
        float s = bmean[t];
        for (int k = 0; k < LATENT; ++k) s += h[k] * Wmean[k * LATENT + t];
        out[t] = s;
    } else {
        int j = t - LATENT;
        float s = blogvar[j];
        for (int k = 0; k < LATENT; ++k) s += h[k] * Wlogvar[k * LATENT + j];
        out[LATENT + j] = s;
    }
}

// ---------------- launch ----------------

extern "C" void kernel_launch(void* const* d_in, const int* in_sizes, int n_in,
                              void* d_out, int out_size, void* d_ws, size_t ws_size,
                              hipStream_t stream) {
    const float* node_features = (const float*)d_in[0];
    const float* conditions    = (const float*)d_in[1];
    const int*   src           = (const int*)d_in[2];
    const int*   dst           = (const int*)d_in[3];
    const float* W1  = (const float*)d_in[4];
    const float* b1  = (const float*)d_in[5];
    const float* W2  = (const float*)d_in[6];
    const float* b2  = (const float*)d_in[7];
    const float* Wfc = (const float*)d_in[8];
    const float* bfc = (const float*)d_in[9];
    const float* Wmean   = (const float*)d_in[10];
    const float* bmean   = (const float*)d_in[11];
    const float* Wlogvar = (const float*)d_in[12];
    const float* blogvar = (const float*)d_in[13];
    float* out = (float*)d_out;

    size_t o = 0;
    auto alloc = [&](size_t bytes) {
        void* p = (char*)d_ws + o;
        o += (bytes + 255) & ~(size_t)255;
        return p;
    };
    int* deg       = (int*)alloc((size_t)N_NODES * 4);
    int* offsets   = (int*)alloc((size_t)(N_NODES + 1) * 4);
    int* incl      = (int*)alloc((size_t)N_NODES * 4);
    int* blocksums = (int*)alloc((size_t)SCAN_BLOCKS * 4);
    int* bcursor   = (int*)alloc((size_t)NB * 4);
    uint* pair_buf = (uint*)alloc((size_t)N_EDGES * 4);
    ushort* csr    = (ushort*)alloc((size_t)N_EDGES * 2);
    float* pooled  = (float*)alloc(HIDDEN * 4);
    ushort* Wt1    = (ushort*)alloc((size_t)HIDDEN * NODE_DIM * 2);
    ushort* Wt2    = (ushort*)alloc((size_t)HIDDEN * HIDDEN * 2);
    uchar* nf_fp8  = (uchar*)alloc((size_t)N_NODES * NODE_DIM);
    uchar* x1_fp8  = (uchar*)alloc((size_t)N_NODES * HIDDEN);
    ushort* agg1   = (ushort*)alloc((size_t)N_NODES * NODE_DIM * 2);
    ushort* agg2   = (ushort*)alloc((size_t)N_NODES * HIDDEN * 2);

    prep_kernel<<<(PREP4 + 255) / 256, 256, 0, stream>>>(
        node_features, W1, W2, nf_fp8, Wt1, Wt2, deg, pooled);

    hist_kernel<<<N_EDGES / 256, 256, 0, stream>>>(dst, deg);
    scan_a_kernel<<<SCAN_BLOCKS, 256, 0, stream>>>(deg, incl, blocksums);
    scan_c_kernel<<<SCAN_BLOCKS, 256, 0, stream>>>(deg, incl, blocksums, offsets, bcursor);
    bucket_kernel<<<P1_GRID, 256, 0, stream>>>(src, dst, bcursor, pair_buf);
    csr_kernel<<<NB, 256, 0, stream>>>(pair_buf, offsets, csr);

    const int AGG_GRID  = (N_NODES * 64 + 255) / 256;
    const int GEMM_GRID = (N_NODES + 31) / 32;   // 1563

    agg_kernel<NODE_DIM><<<AGG_GRID, 256, 0, stream>>>(nf_fp8, offsets, csr, agg1);
    gemm_kernel<NODE_DIM, false><<<GEMM_GRID, 256, 0, stream>>>(agg1, Wt1, b1, x1_fp8, nullptr);

    agg_kernel<HIDDEN><<<AGG_GRID, 256, 0, stream>>>(x1_fp8, offsets, csr, agg2);
    gemm_kernel<HIDDEN, true><<<GEMM_GRID, 256, 0, stream>>>(agg2, Wt2, b2, nullptr, pooled);

    head_kernel<<<1, 256, 0, stream>>>(pooled, conditions, Wfc, bfc,
                                       Wmean, bmean, Wlogvar, blogvar, out);
}

// Round 10
// 204.169 us; speedup vs baseline: 1.0783x; 1.0783x over previous
//
#include <hip/hip_runtime.h>

#define N_NODES   50000
#define N_EDGES   800000
#define NODE_DIM  128
#define HIDDEN    256
#define LATENT    128
#define COND      5

#define SCAN_BLOCKS ((N_NODES + 255) / 256)   // 196
#define NB          196                        // buckets: dst>>8 (256-node ranges)
#define P1_CHUNK    4096
#define P1_GRID     ((N_EDGES + P1_CHUNK - 1) / P1_CHUNK)  // 196

typedef unsigned int uint;
typedef unsigned short ushort;
typedef unsigned char uchar;

typedef __attribute__((ext_vector_type(8))) short bf16x8;
typedef __attribute__((ext_vector_type(4))) float f32x4;

static __device__ __forceinline__ ushort f32_to_bf16(float f) {
    union { float f; uint u; } v; v.f = f;
    uint r = v.u + 0x7FFF + ((v.u >> 16) & 1);   // RNE
    return (ushort)(r >> 16);
}
static __device__ __forceinline__ uint pack_bf16(float lo, float hi) {
    return (uint)f32_to_bf16(lo) | ((uint)f32_to_bf16(hi) << 16);
}

// async global->LDS DMA, 16B per lane; LDS dest = wave-uniform base + lane*16
static __device__ __forceinline__ void gload_lds16(const void* g, void* l) {
    __builtin_amdgcn_global_load_lds(
        (const __attribute__((address_space(1))) unsigned int*)(unsigned long long)(uintptr_t)g,
        (__attribute__((address_space(3))) unsigned int*)(unsigned int)(uintptr_t)l,
        16, 0, 0);
}

// ---------------- fp8 e4m3 helpers (HW cvt with software fallback) ----------------

#if __has_builtin(__builtin_amdgcn_cvt_pk_f32_fp8) && __has_builtin(__builtin_amdgcn_cvt_pk_fp8_f32)
#define HW_FP8 1
#endif

#ifndef HW_FP8
static __device__ __forceinline__ float dec1_fp8(uint b) {
    uint sgn = b & 0x80, mag = b & 0x7f;
    float v;
    if (mag >= 8) {
        union { uint u; float f; } t;
        t.u = (((mag >> 3) + 120) << 23) | ((mag & 7) << 20);
        v = t.f;
    } else {
        v = (float)mag * 0.001953125f;   // 2^-9
    }
    return sgn ? -v : v;
}
static __device__ __forceinline__ uchar enc1_fp8(float f) {
    float a = fabsf(f);
    uint s = (f < 0.f) ? 0x80u : 0u;
    if (!(a >= 0.015625f)) {
        int q = (int)(a * 512.f + 0.5f);
        if (q > 7) q = 7;
        return (uchar)(s | (uint)q);
    }
    if (a >= 448.f) return (uchar)(s | 0x7E);
    union { float f; uint u; } t; t.f = a;
    uint e = (t.u >> 23) - 120;
    uint m = (t.u >> 20) & 7;
    uint rem = t.u & 0xFFFFF;
    uint v = (e << 3) | m;
    if (rem > 0x80000 || (rem == 0x80000 && (v & 1))) v++;
    if (v > 0x7E) v = 0x7E;
    return (uchar)(s | v);
}
#endif

static __device__ __forceinline__ void dec4_add(uint u, float* acc) {
#ifdef HW_FP8
    auto lo = __builtin_amdgcn_cvt_pk_f32_fp8((int)u, false);
    auto hi = __builtin_amdgcn_cvt_pk_f32_fp8((int)u, true);
    acc[0] += lo[0]; acc[1] += lo[1]; acc[2] += hi[0]; acc[3] += hi[1];
#else
    acc[0] += dec1_fp8(u & 0xff);
    acc[1] += dec1_fp8((u >> 8) & 0xff);
    acc[2] += dec1_fp8((u >> 16) & 0xff);
    acc[3] += dec1_fp8(u >> 24);
#endif
}
static __device__ __forceinline__ void dec2_add(uint u, float* acc) {
#ifdef HW_FP8
    auto lo = __builtin_amdgcn_cvt_pk_f32_fp8((int)u, false);
    acc[0] += lo[0]; acc[1] += lo[1];
#else
    acc[0] += dec1_fp8(u & 0xff);
    acc[1] += dec1_fp8((u >> 8) & 0xff);
#endif
}
static __device__ __forceinline__ uint enc2_fp8(float a, float b) {
#ifdef HW_FP8
    return (uint)__builtin_amdgcn_cvt_pk_fp8_f32(a, b, 0, false) & 0xFFFFu;
#else
    return (uint)enc1_fp8(a) | ((uint)enc1_fp8(b) << 8);
#endif
}
static __device__ __forceinline__ uchar enc1(float v) {
#ifdef HW_FP8
    return (uchar)(__builtin_amdgcn_cvt_pk_fp8_f32(v, v, 0, false) & 0xff);
#else
    return enc1_fp8(v);
#endif
}

// ---------------- prep: nf -> fp8, W transpose (bf16), deg/pooled zero ----------------

#define NF4   (N_NODES * NODE_DIM / 4)            // 1,600,000
#define PREP1 (NF4 + NODE_DIM * HIDDEN)           // + 32768
#define PREP2 (PREP1 + HIDDEN * HIDDEN)           // + 65536
#define PREP3 (PREP2 + N_NODES)                   // + 50000 (deg zero)
#define PREP4 (PREP3 + HIDDEN)                    // + 256 (pooled zero)

__global__ void prep_kernel(const float* __restrict__ nf,
                            const float* __restrict__ W1, const float* __restrict__ W2,
                            uchar* __restrict__ nf_fp8,
                            ushort* __restrict__ Wt1, ushort* __restrict__ Wt2,
                            int* __restrict__ deg, float* __restrict__ pooled) {
    int id = blockIdx.x * blockDim.x + threadIdx.x;
    if (id < NF4) {
        float4 v = reinterpret_cast<const float4*>(nf)[id];
        uint w = enc2_fp8(v.x, v.y) | (enc2_fp8(v.z, v.w) << 16);
        reinterpret_cast<uint*>(nf_fp8)[id] = w;
    } else if (id < PREP1) {
        int i = id - NF4;
        int k = i >> 8, c = i & 255;
        Wt1[c * NODE_DIM + k] = f32_to_bf16(W1[i]);
    } else if (id < PREP2) {
        int i = id - PREP1;
        int k = i >> 8, c = i & 255;
        Wt2[c * HIDDEN + k] = f32_to_bf16(W2[i]);
    } else if (id < PREP3) {
        deg[id - PREP2] = 0;
    } else if (id < PREP4) {
        pooled[id - PREP3] = 0.f;
    }
}

// ---------------- CSR build ----------------

__global__ void hist_kernel(const int* __restrict__ dst, int* __restrict__ deg) {
    int e = blockIdx.x * blockDim.x + threadIdx.x;
    if (e < N_EDGES) atomicAdd(&deg[dst[e]], 1);
}

__global__ void scan_a_kernel(const int* __restrict__ deg, int* __restrict__ incl,
                              int* __restrict__ blocksums) {
    int i = blockIdx.x * 256 + threadIdx.x;
    int lane = threadIdx.x & 63;
    int w    = threadIdx.x >> 6;
    int v = (i < N_NODES) ? deg[i] : 0;
    int s = v;
#pragma unroll
    for (int d = 1; d < 64; d <<= 1) {
        int t = __shfl_up(s, d);
        if (lane >= d) s += t;
    }
    __shared__ int wsum[4];
    if (lane == 63) wsum[w] = s;
    __syncthreads();
    int add = 0;
    for (int k = 0; k < w; ++k) add += wsum[k];
    s += add;
    if (i < N_NODES) incl[i] = s;
    if (threadIdx.x == 255) blocksums[blockIdx.x] = s;
}

__global__ void scan_c_kernel(const int* __restrict__ deg, const int* __restrict__ incl,
                              const int* __restrict__ blocksums,
                              int* __restrict__ offsets, int* __restrict__ bcursor) {
    __shared__ int s[256];
    int t = threadIdx.x;
    s[t] = (t < SCAN_BLOCKS) ? blocksums[t] : 0;
    __syncthreads();
    for (int off = 1; off < 256; off <<= 1) {
        int v = (t >= off) ? s[t - off] : 0;
        __syncthreads();
        s[t] += v;
        __syncthreads();
    }
    int bo = (blockIdx.x == 0) ? 0 : s[blockIdx.x - 1];
    int i = blockIdx.x * 256 + t;
    if (i < N_NODES) {
        int inc = incl[i];
        int off = bo + inc - deg[i];
        offsets[i] = off;
        if ((i & 255) == 0) bcursor[i >> 8] = off;
        if (i == N_NODES - 1) offsets[N_NODES] = bo + inc;
    }
}

// ---------------- pass 1: bucket multi-split ----------------

__global__ __launch_bounds__(256) void bucket_kernel(const int* __restrict__ src,
                                                     const int* __restrict__ dst,
                                                     int* __restrict__ bcursor,
                                                     uint* __restrict__ pair_buf) {
    __shared__ int cnt[NB];
    __shared__ int gbase[NB];
    const int t = threadIdx.x;
    for (int i = t; i < NB; i += 256) cnt[i] = 0;
    __syncthreads();

    const int base = blockIdx.x * P1_CHUNK;
    uint pk[16];
    int  bk[16], lr[16];
    bool ok[16];
#pragma unroll
    for (int i = 0; i < 16; ++i) {
        int e = base + i * 256 + t;
        ok[i] = e < N_EDGES;
        if (ok[i]) {
            int s = src[e], d = dst[e];
            pk[i] = (uint)s | ((uint)d << 16);
            bk[i] = d >> 8;
        }
    }
#pragma unroll
    for (int i = 0; i < 16; ++i)
        if (ok[i]) lr[i] = atomicAdd(&cnt[bk[i]], 1);
    __syncthreads();
    if (t < NB) {
        int c = cnt[t];
        gbase[t] = (c > 0) ? atomicAdd(&bcursor[t], c) : 0;
    }
    __syncthreads();
#pragma unroll
    for (int i = 0; i < 16; ++i)
        if (ok[i]) pair_buf[gbase[bk[i]] + lr[i]] = pk[i];
}

// ---------------- pass 2: block-local CSR scatter ----------------

__global__ __launch_bounds__(256) void csr_kernel(const uint* __restrict__ pair_buf,
                                                  const int* __restrict__ offsets,
                                                  ushort* __restrict__ csr) {
    __shared__ int loff[257];
    __shared__ int lcur[256];
    const int b  = blockIdx.x;
    const int t  = threadIdx.x;
    const int n0 = b << 8;
    int node = n0 + t;
    loff[t] = offsets[node < N_NODES ? node : N_NODES];
    if (t == 0) {
        int ne = n0 + 256;
        loff[256] = offsets[ne < N_NODES ? ne : N_NODES];
    }
    lcur[t] = 0;
    __syncthreads();
    const int e0 = loff[0], e1 = loff[256];
    for (int j = e0 + t; j < e1; j += 256) {
        uint p = pair_buf[j];
        int dl = (int)(p >> 16) - n0;
        int r = atomicAdd(&lcur[dl], 1);
        csr[loff[dl] + r] = (ushort)(p & 0xFFFFu);
    }
}

// ---------------- aggregation: wave per node, fp8 gather, 16-deep load pipeline ----------------

template <int D>
__global__ __launch_bounds__(256) void agg_kernel(const uchar* __restrict__ x,
                                                  const int* __restrict__ offsets,
                                                  const ushort* __restrict__ csr,
                                                  ushort* __restrict__ out) {
    constexpr int BPL = D / 64;   // bytes per lane: 2 or 4
    int node = (blockIdx.x * blockDim.x + threadIdx.x) >> 6;
    int lane = threadIdx.x & 63;
    if (node >= N_NODES) return;
    int j0 = __builtin_amdgcn_readfirstlane(offsets[node]);
    int j1 = __builtin_amdgcn_readfirstlane(offsets[node + 1]);

    float acc[BPL];
#pragma unroll
    for (int i = 0; i < BPL; ++i) acc[i] = 0.f;

    const uchar* base = x + lane * BPL;
    const int il = lane & 15;

    int idxv = (j0 + il < j1) ? (int)csr[j0 + il] : 0;

    for (int jb = j0; jb < j1; jb += 16) {
        int idxn = (jb + 16 + il < j1) ? (int)csr[jb + 16 + il] : 0;
        int n = j1 - jb; n = (n > 16) ? 16 : n;
        uint u[16];
        if (n == 16) {
#pragma unroll
            for (int i = 0; i < 16; ++i) {
                int s = __shfl(idxv, i);
                if constexpr (BPL == 4)
                    u[i] = *reinterpret_cast<const uint*>(base + (size_t)s * D);
                else
                    u[i] = *reinterpret_cast<const ushort*>(base + (size_t)s * D);
            }
#pragma unroll
            for (int i = 0; i < 16; ++i) {
                if constexpr (BPL == 4) dec4_add(u[i], acc); else dec2_add(u[i], acc);
            }
        } else {
#pragma unroll
            for (int i = 0; i < 16; ++i) {
                if (i < n) {
                    int s = __shfl(idxv, i);
                    if constexpr (BPL == 4)
                        u[i] = *reinterpret_cast<const uint*>(base + (size_t)s * D);
                    else
                        u[i] = *reinterpret_cast<const ushort*>(base + (size_t)s * D);
                }
            }
#pragma unroll
            for (int i = 0; i < 16; ++i) {
                if (i < n) {
                    if constexpr (BPL == 4) dec4_add(u[i], acc); else dec2_add(u[i], acc);
                }
            }
        }
        idxv = idxn;
    }

    if constexpr (BPL == 4) {
        uint2 o;
        o.x = pack_bf16(acc[0], acc[1]);
        o.y = pack_bf16(acc[2], acc[3]);
        *reinterpret_cast<uint2*>(out + (size_t)node * D + lane * 4) = o;
    } else {
        *reinterpret_cast<uint*>(out + (size_t)node * D + lane * 2) = pack_bf16(acc[0], acc[1]);
    }
}

// ---------------- MFMA GEMM v3: LDS-staged (m97-lite) ----------------
// block = 64 rows x 256 cols (grid 782), 4 waves; wave = 64x64 (4x4 fragments).
// BK=32, double-buffered LDS staged via global_load_lds (async DMA).
// LDS layout per buffer (20480B): A [kg][row][16B] @0..4095; W [kg][col][16B] @4096..20479.
// Staging: 20 x 1KB chunks/step (4 A + 16 W), 5 per wave, linear lane order.
// A rows need +64 rows of padded allocation (reads masked at epilogue only).

template <int K, bool POOL>
__global__ __launch_bounds__(256) void gemm_lds_kernel(const ushort* __restrict__ A,
                                                       const ushort* __restrict__ Wt,
                                                       const float* __restrict__ bias,
                                                       uchar* __restrict__ Xout,
                                                       float* __restrict__ pooled) {
    constexpr int BUFB  = 20480;
    constexpr int NSTEP = K / 32;
    __shared__ uchar lds_raw[2 * BUFB];

    const int t    = threadIdx.x;
    const int lane = t & 63;
    const int wv   = t >> 6;
    const int row0 = blockIdx.x * 64;
    const int fr   = lane & 15;
    const int kgl  = lane >> 4;

    const ushort* Arow = A + (size_t)(row0 + lane) * K;   // per-lane source row

    auto stage = [&](int buf, int k0) {
#pragma unroll
        for (int j = 0; j < 5; ++j) {
            const int c = wv * 5 + j;           // 0..19, wave-uniform
            if (c < 4) {
                gload_lds16(Arow + k0 + c * 8,
                            &lds_raw[buf * BUFB + c * 1024]);
            } else {
                const int w  = c - 4;
                const int kg = w >> 2, cc = w & 3;
                gload_lds16(Wt + (size_t)(cc * 64 + lane) * K + k0 + kg * 8,
                            &lds_raw[buf * BUFB + 4096 + kg * 4096 + cc * 1024]);
            }
        }
    };

    f32x4 acc[4][4];
#pragma unroll
    for (int rt = 0; rt < 4; ++rt)
#pragma unroll
        for (int ct = 0; ct < 4; ++ct)
            acc[rt][ct] = (f32x4){0.f, 0.f, 0.f, 0.f};

    stage(0, 0);
#pragma unroll
    for (int ks = 0; ks < NSTEP; ++ks) {
        const int buf = ks & 1;
        if (ks + 1 < NSTEP) stage(buf ^ 1, (ks + 1) * 32);
        __syncthreads();                         // drains vmcnt -> buf ready
        const uchar* bb = &lds_raw[buf * BUFB];
        bf16x8 af[4], bfv[4];
#pragma unroll
        for (int rt = 0; rt < 4; ++rt)
            af[rt] = *reinterpret_cast<const bf16x8*>(bb + kgl * 1024 + (rt * 16 + fr) * 16);
#pragma unroll
        for (int ct = 0; ct < 4; ++ct)
            bfv[ct] = *reinterpret_cast<const bf16x8*>(bb + 4096 + kgl * 4096 + (wv * 64 + ct * 16 + fr) * 16);
#pragma unroll
        for (int rt = 0; rt < 4; ++rt)
#pragma unroll
            for (int ct = 0; ct < 4; ++ct)
                acc[rt][ct] = __builtin_amdgcn_mfma_f32_16x16x32_bf16(af[rt], bfv[ct], acc[rt][ct], 0, 0, 0);
        __syncthreads();                         // all waves done reading buf
    }

    const int col0 = wv * 64;
    float bcol[4];
#pragma unroll
    for (int ct = 0; ct < 4; ++ct) bcol[ct] = bias[col0 + ct * 16 + fr];
    const int mrow = (lane >> 4) * 4;

    if constexpr (POOL) {
        float cs[4] = {0.f, 0.f, 0.f, 0.f};
#pragma unroll
        for (int rt = 0; rt < 4; ++rt) {
#pragma unroll
            for (int e = 0; e < 4; ++e) {
                int m = row0 + rt * 16 + mrow + e;
                if (m < N_NODES) {
#pragma unroll
                    for (int ct = 0; ct < 4; ++ct)
                        cs[ct] += fmaxf(acc[rt][ct][e] + bcol[ct], 0.f);
                }
            }
        }
#pragma unroll
        for (int ct = 0; ct < 4; ++ct) {
            cs[ct] += __shfl_xor(cs[ct], 16);
            cs[ct] += __shfl_xor(cs[ct], 32);
        }
        if (lane < 16) {
#pragma unroll
            for (int ct = 0; ct < 4; ++ct)
                atomicAdd(&pooled[col0 + ct * 16 + lane], cs[ct]);
        }
    } else {
#pragma unroll
        for (int rt = 0; rt < 4; ++rt) {
#pragma unroll
            for (int e = 0; e < 4; ++e) {
                int m = row0 + rt * 16 + mrow + e;
                if (m < N_NODES) {
#pragma unroll
                    for (int ct = 0; ct < 4; ++ct) {
                        float v = fmaxf(acc[rt][ct][e] + bcol[ct], 0.f);
                        Xout[(size_t)m * HIDDEN + col0 + ct * 16 + fr] = enc1(v);
                    }
                }
            }
        }
    }
}

// ---------------- head MLP ----------------

__global__ void head_kernel(const float* __restrict__ pooled_sum, const float* __restrict__ cond,
                            const float* __restrict__ Wfc, const float* __restrict__ bfc,
                            const float* __restrict__ Wmean, const float* __restrict__ bmean,
                            const float* __restrict__ Wlogvar, const float* __restrict__ blogvar,
                            float* __restrict__ out) {
    __shared__ float v[HIDDEN + COND];
    __shared__ float h[LATENT];
    int t = threadIdx.x;
    if (t < HIDDEN) v[t] = pooled_sum[t] * (1.0f / N_NODES);
    if (t < COND) v[HIDDEN + t] = cond[t];
    __syncthreads();
    if (t < LATENT) {
        float s = bfc[t];
        for (int k = 0; k < HIDDEN + COND; ++k) s += v[k] * Wfc[k * LATENT + t];
        h[t] = fmaxf(s, 0.f);
    }
    __syncthreads();
    if (t < LATENT) {
        float s = bmean[t];
        for (int k = 0; k < LATENT; ++k) s += h[k] * Wmean[k * LATENT + t];
        out[t] = s;
    } else {
        int j = t - LATENT;
        float s = blogvar[j];
        for (int k = 0; k < LATENT; ++k) s += h[k] * Wlogvar[k * LATENT + j];
        out[LATENT + j] = s;
    }
}

// ---------------- launch ----------------

extern "C" void kernel_launch(void* const* d_in, const int* in_sizes, int n_in,
                              void* d_out, int out_size, void* d_ws, size_t ws_size,
                              hipStream_t stream) {
    const float* node_features = (const float*)d_in[0];
    const float* conditions    = (const float*)d_in[1];
    const int*   src           = (const int*)d_in[2];
    const int*   dst           = (const int*)d_in[3];
    const float* W1  = (const float*)d_in[4];
    const float* b1  = (const float*)d_in[5];
    const float* W2  = (const float*)d_in[6];
    const float* b2  = (const float*)d_in[7];
    const float* Wfc = (const float*)d_in[8];
    const float* bfc = (const float*)d_in[9];
    const float* Wmean   = (const float*)d_in[10];
    const float* bmean   = (const float*)d_in[11];
    const float* Wlogvar = (const float*)d_in[12];
    const float* blogvar = (const float*)d_in[13];
    float* out = (float*)d_out;

    size_t o = 0;
    auto alloc = [&](size_t bytes) {
        void* p = (char*)d_ws + o;
        o += (bytes + 255) & ~(size_t)255;
        return p;
    };
    int* deg       = (int*)alloc((size_t)N_NODES * 4);
    int* offsets   = (int*)alloc((size_t)(N_NODES + 1) * 4);
    int* incl      = (int*)alloc((size_t)N_NODES * 4);
    int* blocksums = (int*)alloc((size_t)SCAN_BLOCKS * 4);
    int* bcursor   = (int*)alloc((size_t)NB * 4);
    uint* pair_buf = (uint*)alloc((size_t)N_EDGES * 4);
    ushort* csr    = (ushort*)alloc((size_t)N_EDGES * 2);
    float* pooled  = (float*)alloc(HIDDEN * 4);
    ushort* Wt1    = (ushort*)alloc((size_t)HIDDEN * NODE_DIM * 2);
    ushort* Wt2    = (ushort*)alloc((size_t)HIDDEN * HIDDEN * 2);
    uchar* nf_fp8  = (uchar*)alloc((size_t)N_NODES * NODE_DIM);
    uchar* x1_fp8  = (uchar*)alloc((size_t)N_NODES * HIDDEN);
    // +64 rows pad: gemm staging reads past row 49999 (results masked)
    ushort* agg1   = (ushort*)alloc((size_t)(N_NODES + 64) * NODE_DIM * 2);
    ushort* agg2   = (ushort*)alloc((size_t)(N_NODES + 64) * HIDDEN * 2);

    prep_kernel<<<(PREP4 + 255) / 256, 256, 0, stream>>>(
        node_features, W1, W2, nf_fp8, Wt1, Wt2, deg, pooled);

    hist_kernel<<<N_EDGES / 256, 256, 0, stream>>>(dst, deg);
    scan_a_kernel<<<SCAN_BLOCKS, 256, 0, stream>>>(deg, incl, blocksums);
    scan_c_kernel<<<SCAN_BLOCKS, 256, 0, stream>>>(deg, incl, blocksums, offsets, bcursor);
    bucket_kernel<<<P1_GRID, 256, 0, stream>>>(src, dst, bcursor, pair_buf);
    csr_kernel<<<NB, 256, 0, stream>>>(pair_buf, offsets, csr);

    const int AGG_GRID  = (N_NODES * 64 + 255) / 256;
    const int GEMM_GRID = (N_NODES + 63) / 64;   // 782

    agg_kernel<NODE_DIM><<<AGG_GRID, 256, 0, stream>>>(nf_fp8, offsets, csr, agg1);
    gemm_lds_kernel<NODE_DIM, false><<<GEMM_GRID, 256, 0, stream>>>(agg1, Wt1, b1, x1_fp8, nullptr);

    agg_kernel<HIDDEN><<<AGG_GRID, 256, 0, stream>>>(x1_fp8, offsets, csr, agg2);
    gemm_lds_kernel<HIDDEN, true><<<GEMM_GRID, 256, 0, stream>>>(agg2, Wt2, b2, nullptr, pooled);

    head_kernel<<<1, 256, 0, stream>>>(pooled, conditions, Wfc, bfc,
                                       Wmean, bmean, Wlogvar, blogvar, out);
}

// Round 11
// 187.883 us; speedup vs baseline: 1.1718x; 1.0867x over previous
//
#include <hip/hip_runtime.h>

#define N_NODES   50000
#define N_EDGES   800000
#define NODE_DIM  128
#define HIDDEN    256
#define LATENT    128
#define COND      5

#define SCAN_BLOCKS ((N_NODES + 255) / 256)   // 196
#define NB          196                        // buckets: dst>>8 (256-node ranges)
#define P1_CHUNK    4096
#define P1_GRID     ((N_EDGES + P1_CHUNK - 1) / P1_CHUNK)  // 196

typedef unsigned int uint;
typedef unsigned short ushort;
typedef unsigned char uchar;

typedef __attribute__((ext_vector_type(8))) short bf16x8;
typedef __attribute__((ext_vector_type(4))) float f32x4;

static __device__ __forceinline__ ushort f32_to_bf16(float f) {
    union { float f; uint u; } v; v.f = f;
    uint r = v.u + 0x7FFF + ((v.u >> 16) & 1);   // RNE
    return (ushort)(r >> 16);
}
static __device__ __forceinline__ uint pack_bf16(float lo, float hi) {
    return (uint)f32_to_bf16(lo) | ((uint)f32_to_bf16(hi) << 16);
}

// async global->LDS DMA, 16B per lane; LDS dest = wave-uniform base + lane*16
static __device__ __forceinline__ void gload_lds16(const void* g, void* l) {
    __builtin_amdgcn_global_load_lds(
        (const __attribute__((address_space(1))) unsigned int*)(unsigned long long)(uintptr_t)g,
        (__attribute__((address_space(3))) unsigned int*)(unsigned int)(uintptr_t)l,
        16, 0, 0);
}

// ---------------- fp8 e4m3 helpers (HW cvt with software fallback) ----------------

#if __has_builtin(__builtin_amdgcn_cvt_pk_f32_fp8) && __has_builtin(__builtin_amdgcn_cvt_pk_fp8_f32)
#define HW_FP8 1
#endif

#ifndef HW_FP8
static __device__ __forceinline__ float dec1_fp8(uint b) {
    uint sgn = b & 0x80, mag = b & 0x7f;
    float v;
    if (mag >= 8) {
        union { uint u; float f; } t;
        t.u = (((mag >> 3) + 120) << 23) | ((mag & 7) << 20);
        v = t.f;
    } else {
        v = (float)mag * 0.001953125f;   // 2^-9
    }
    return sgn ? -v : v;
}
static __device__ __forceinline__ uchar enc1_fp8(float f) {
    float a = fabsf(f);
    uint s = (f < 0.f) ? 0x80u : 0u;
    if (!(a >= 0.015625f)) {
        int q = (int)(a * 512.f + 0.5f);
        if (q > 7) q = 7;
        return (uchar)(s | (uint)q);
    }
    if (a >= 448.f) return (uchar)(s | 0x7E);
    union { float f; uint u; } t; t.f = a;
    uint e = (t.u >> 23) - 120;
    uint m = (t.u >> 20) & 7;
    uint rem = t.u & 0xFFFFF;
    uint v = (e << 3) | m;
    if (rem > 0x80000 || (rem == 0x80000 && (v & 1))) v++;
    if (v > 0x7E) v = 0x7E;
    return (uchar)(s | v);
}
#endif

static __device__ __forceinline__ void dec4_add(uint u, float* acc) {
#ifdef HW_FP8
    auto lo = __builtin_amdgcn_cvt_pk_f32_fp8((int)u, false);
    auto hi = __builtin_amdgcn_cvt_pk_f32_fp8((int)u, true);
    acc[0] += lo[0]; acc[1] += lo[1]; acc[2] += hi[0]; acc[3] += hi[1];
#else
    acc[0] += dec1_fp8(u & 0xff);
    acc[1] += dec1_fp8((u >> 8) & 0xff);
    acc[2] += dec1_fp8((u >> 16) & 0xff);
    acc[3] += dec1_fp8(u >> 24);
#endif
}
static __device__ __forceinline__ void dec2_add(uint u, float* acc) {
#ifdef HW_FP8
    auto lo = __builtin_amdgcn_cvt_pk_f32_fp8((int)u, false);
    acc[0] += lo[0]; acc[1] += lo[1];
#else
    acc[0] += dec1_fp8(u & 0xff);
    acc[1] += dec1_fp8((u >> 8) & 0xff);
#endif
}
static __device__ __forceinline__ uint enc2_fp8(float a, float b) {
#ifdef HW_FP8
    return (uint)__builtin_amdgcn_cvt_pk_fp8_f32(a, b, 0, false) & 0xFFFFu;
#else
    return (uint)enc1_fp8(a) | ((uint)enc1_fp8(b) << 8);
#endif
}
static __device__ __forceinline__ uchar enc1(float v) {
#ifdef HW_FP8
    return (uchar)(__builtin_amdgcn_cvt_pk_fp8_f32(v, v, 0, false) & 0xff);
#else
    return enc1_fp8(v);
#endif
}

// ---------------- prep: nf -> fp8, W -> DMA-packed bf16 chunks, deg/pooled zero ----------------
// Wst layout (ushort): [kstep][chunk w=kg*4+cc][col' 0..63][k' 0..7]
//   element (k, c): ks=k>>5, kg=(k&31)>>3, k'=k&7, cc=c>>6, col'=c&63
//   idx = (((ks*16) + (kg*4+cc))*64 + col')*8 + k'
// Each 512-ushort (1KB) chunk is exactly one wave gload_lds16 (contiguous), and
// lands in LDS in fragment order [kg][col][16B].

#define NF4   (N_NODES * NODE_DIM / 4)            // 1,600,000
#define PREP1 (NF4 + NODE_DIM * HIDDEN)           // + 32768
#define PREP2 (PREP1 + HIDDEN * HIDDEN)           // + 65536
#define PREP3 (PREP2 + N_NODES)                   // + 50000 (deg zero)
#define PREP4 (PREP3 + HIDDEN)                    // + 256 (pooled zero)

__global__ void prep_kernel(const float* __restrict__ nf,
                            const float* __restrict__ W1, const float* __restrict__ W2,
                            uchar* __restrict__ nf_fp8,
                            ushort* __restrict__ Wst1, ushort* __restrict__ Wst2,
                            int* __restrict__ deg, float* __restrict__ pooled) {
    int id = blockIdx.x * blockDim.x + threadIdx.x;
    if (id < NF4) {
        float4 v = reinterpret_cast<const float4*>(nf)[id];
        uint w = enc2_fp8(v.x, v.y) | (enc2_fp8(v.z, v.w) << 16);
        reinterpret_cast<uint*>(nf_fp8)[id] = w;
    } else if (id < PREP1) {
        int i = id - NF4;
        int k = i >> 8, c = i & 255;
        int idx = ((((k >> 5) * 16) + (((k & 31) >> 3) * 4 + (c >> 6))) * 64 + (c & 63)) * 8 + (k & 7);
        Wst1[idx] = f32_to_bf16(W1[i]);
    } else if (id < PREP2) {
        int i = id - PREP1;
        int k = i >> 8, c = i & 255;
        int idx = ((((k >> 5) * 16) + (((k & 31) >> 3) * 4 + (c >> 6))) * 64 + (c & 63)) * 8 + (k & 7);
        Wst2[idx] = f32_to_bf16(W2[i]);
    } else if (id < PREP3) {
        deg[id - PREP2] = 0;
    } else if (id < PREP4) {
        pooled[id - PREP3] = 0.f;
    }
}

// ---------------- CSR build ----------------

__global__ void hist_kernel(const int* __restrict__ dst, int* __restrict__ deg) {
    int e = blockIdx.x * blockDim.x + threadIdx.x;
    if (e < N_EDGES) atomicAdd(&deg[dst[e]], 1);
}

__global__ void scan_a_kernel(const int* __restrict__ deg, int* __restrict__ incl,
                              int* __restrict__ blocksums) {
    int i = blockIdx.x * 256 + threadIdx.x;
    int lane = threadIdx.x & 63;
    int w    = threadIdx.x >> 6;
    int v = (i < N_NODES) ? deg[i] : 0;
    int s = v;
#pragma unroll
    for (int d = 1; d < 64; d <<= 1) {
        int t = __shfl_up(s, d);
        if (lane >= d) s += t;
    }
    __shared__ int wsum[4];
    if (lane == 63) wsum[w] = s;
    __syncthreads();
    int add = 0;
    for (int k = 0; k < w; ++k) add += wsum[k];
    s += add;
    if (i < N_NODES) incl[i] = s;
    if (threadIdx.x == 255) blocksums[blockIdx.x] = s;
}

__global__ void scan_c_kernel(const int* __restrict__ deg, const int* __restrict__ incl,
                              const int* __restrict__ blocksums,
                              int* __restrict__ offsets, int* __restrict__ bcursor) {
    __shared__ int s[256];
    int t = threadIdx.x;
    s[t] = (t < SCAN_BLOCKS) ? blocksums[t] : 0;
    __syncthreads();
    for (int off = 1; off < 256; off <<= 1) {
        int v = (t >= off) ? s[t - off] : 0;
        __syncthreads();
        s[t] += v;
        __syncthreads();
    }
    int bo = (blockIdx.x == 0) ? 0 : s[blockIdx.x - 1];
    int i = blockIdx.x * 256 + t;
    if (i < N_NODES) {
        int inc = incl[i];
        int off = bo + inc - deg[i];
        offsets[i] = off;
        if ((i & 255) == 0) bcursor[i >> 8] = off;
        if (i == N_NODES - 1) offsets[N_NODES] = bo + inc;
    }
}

// ---------------- pass 1: bucket multi-split ----------------

__global__ __launch_bounds__(256) void bucket_kernel(const int* __restrict__ src,
                                                     const int* __restrict__ dst,
                                                     int* __restrict__ bcursor,
                                                     uint* __restrict__ pair_buf) {
    __shared__ int cnt[NB];
    __shared__ int gbase[NB];
    const int t = threadIdx.x;
    for (int i = t; i < NB; i += 256) cnt[i] = 0;
    __syncthreads();

    const int base = blockIdx.x * P1_CHUNK;
    uint pk[16];
    int  bk[16], lr[16];
    bool ok[16];
#pragma unroll
    for (int i = 0; i < 16; ++i) {
        int e = base + i * 256 + t;
        ok[i] = e < N_EDGES;
        if (ok[i]) {
            int s = src[e], d = dst[e];
            pk[i] = (uint)s | ((uint)d << 16);
            bk[i] = d >> 8;
        }
    }
#pragma unroll
    for (int i = 0; i < 16; ++i)
        if (ok[i]) lr[i] = atomicAdd(&cnt[bk[i]], 1);
    __syncthreads();
    if (t < NB) {
        int c = cnt[t];
        gbase[t] = (c > 0) ? atomicAdd(&bcursor[t], c) : 0;
    }
    __syncthreads();
#pragma unroll
    for (int i = 0; i < 16; ++i)
        if (ok[i]) pair_buf[gbase[bk[i]] + lr[i]] = pk[i];
}

// ---------------- pass 2: block-local CSR scatter ----------------

__global__ __launch_bounds__(256) void csr_kernel(const uint* __restrict__ pair_buf,
                                                  const int* __restrict__ offsets,
                                                  ushort* __restrict__ csr) {
    __shared__ int loff[257];
    __shared__ int lcur[256];
    const int b  = blockIdx.x;
    const int t  = threadIdx.x;
    const int n0 = b << 8;
    int node = n0 + t;
    loff[t] = offsets[node < N_NODES ? node : N_NODES];
    if (t == 0) {
        int ne = n0 + 256;
        loff[256] = offsets[ne < N_NODES ? ne : N_NODES];
    }
    lcur[t] = 0;
    __syncthreads();
    const int e0 = loff[0], e1 = loff[256];
    for (int j = e0 + t; j < e1; j += 256) {
        uint p = pair_buf[j];
        int dl = (int)(p >> 16) - n0;
        int r = atomicAdd(&lcur[dl], 1);
        csr[loff[dl] + r] = (ushort)(p & 0xFFFFu);
    }
}

// ---------------- aggregation: wave per node, fp8 gather, 16-deep load pipeline ----------------

template <int D>
__global__ __launch_bounds__(256) void agg_kernel(const uchar* __restrict__ x,
                                                  const int* __restrict__ offsets,
                                                  const ushort* __restrict__ csr,
                                                  ushort* __restrict__ out) {
    constexpr int BPL = D / 64;   // bytes per lane: 2 or 4
    int node = (blockIdx.x * blockDim.x + threadIdx.x) >> 6;
    int lane = threadIdx.x & 63;
    if (node >= N_NODES) return;
    int j0 = __builtin_amdgcn_readfirstlane(offsets[node]);
    int j1 = __builtin_amdgcn_readfirstlane(offsets[node + 1]);

    float acc[BPL];
#pragma unroll
    for (int i = 0; i < BPL; ++i) acc[i] = 0.f;

    const uchar* base = x + lane * BPL;
    const int il = lane & 15;

    int idxv = (j0 + il < j1) ? (int)csr[j0 + il] : 0;

    for (int jb = j0; jb < j1; jb += 16) {
        int idxn = (jb + 16 + il < j1) ? (int)csr[jb + 16 + il] : 0;
        int n = j1 - jb; n = (n > 16) ? 16 : n;
        uint u[16];
        if (n == 16) {
#pragma unroll
            for (int i = 0; i < 16; ++i) {
                int s = __shfl(idxv, i);
                if constexpr (BPL == 4)
                    u[i] = *reinterpret_cast<const uint*>(base + (size_t)s * D);
                else
                    u[i] = *reinterpret_cast<const ushort*>(base + (size_t)s * D);
            }
#pragma unroll
            for (int i = 0; i < 16; ++i) {
                if constexpr (BPL == 4) dec4_add(u[i], acc); else dec2_add(u[i], acc);
            }
        } else {
#pragma unroll
            for (int i = 0; i < 16; ++i) {
                if (i < n) {
                    int s = __shfl(idxv, i);
                    if constexpr (BPL == 4)
                        u[i] = *reinterpret_cast<const uint*>(base + (size_t)s * D);
                    else
                        u[i] = *reinterpret_cast<const ushort*>(base + (size_t)s * D);
                }
            }
#pragma unroll
            for (int i = 0; i < 16; ++i) {
                if (i < n) {
                    if constexpr (BPL == 4) dec4_add(u[i], acc); else dec2_add(u[i], acc);
                }
            }
        }
        idxv = idxn;
    }

    if constexpr (BPL == 4) {
        uint2 o;
        o.x = pack_bf16(acc[0], acc[1]);
        o.y = pack_bf16(acc[2], acc[3]);
        *reinterpret_cast<uint2*>(out + (size_t)node * D + lane * 4) = o;
    } else {
        *reinterpret_cast<uint*>(out + (size_t)node * D + lane * 2) = pack_bf16(acc[0], acc[1]);
    }
}

// ---------------- MFMA GEMM v4: LDS-staged with COALESCED DMA ----------------
// block = 64 rows x 256 cols (grid 782), 4 waves; wave = 64x64 (4x4 fragments).
// BK=32, double-buffered LDS via global_load_lds.
// LDS per buffer (20480B):
//   A: chunk rt (0..3) @ rt*1024: [row' 0..15][kgroup 0..3][16B]
//      source: lane l -> row row0+rt*16+(l>>2), k-bytes (k0+(l&3)*8)*2 — 4-lane
//      groups read full 64B lines (fully coalesced).
//   W: chunk w (0..15) @ 4096+w*1024: packed Wst chunk, 1KB CONTIGUOUS in global.
// Fragment reads: af[rt] @ rt*1024 + fr*64 + kgl*16;
//                 bfv[ct] @ 4096 + kgl*4096 + (wv*64+ct*16+fr)*16.

template <int K, bool POOL>
__global__ __launch_bounds__(256) void gemm_lds_kernel(const ushort* __restrict__ A,
                                                       const ushort* __restrict__ Wst,
                                                       const float* __restrict__ bias,
                                                       uchar* __restrict__ Xout,
                                                       float* __restrict__ pooled) {
    constexpr int BUFB  = 20480;
    constexpr int NSTEP = K / 32;
    __shared__ uchar lds_raw[2 * BUFB];

    const int t    = threadIdx.x;
    const int lane = t & 63;
    const int wv   = t >> 6;
    const int row0 = blockIdx.x * 64;
    const int fr   = lane & 15;
    const int kgl  = lane >> 4;

    auto stage = [&](int buf, int ks) {
#pragma unroll
        for (int j = 0; j < 5; ++j) {
            const int c = wv * 5 + j;           // 0..19, wave-uniform
            if (c < 4) {
                gload_lds16(A + (size_t)(row0 + c * 16 + (lane >> 2)) * K + ks * 32 + (lane & 3) * 8,
                            &lds_raw[buf * BUFB + c * 1024]);
            } else {
                const int w = c - 4;            // 0..15
                gload_lds16(Wst + ((size_t)ks * 16 + w) * 512 + lane * 8,
                            &lds_raw[buf * BUFB + 4096 + w * 1024]);
            }
        }
    };

    f32x4 acc[4][4];
#pragma unroll
    for (int rt = 0; rt < 4; ++rt)
#pragma unroll
        for (int ct = 0; ct < 4; ++ct)
            acc[rt][ct] = (f32x4){0.f, 0.f, 0.f, 0.f};

    stage(0, 0);
#pragma unroll
    for (int ks = 0; ks < NSTEP; ++ks) {
        const int buf = ks & 1;
        if (ks + 1 < NSTEP) stage(buf ^ 1, ks + 1);
        __syncthreads();                         // drains vmcnt -> buf ready
        const uchar* bb = &lds_raw[buf * BUFB];
        bf16x8 af[4], bfv[4];
#pragma unroll
        for (int rt = 0; rt < 4; ++rt)
            af[rt] = *reinterpret_cast<const bf16x8*>(bb + rt * 1024 + fr * 64 + kgl * 16);
#pragma unroll
        for (int ct = 0; ct < 4; ++ct)
            bfv[ct] = *reinterpret_cast<const bf16x8*>(bb + 4096 + kgl * 4096 + (wv * 64 + ct * 16 + fr) * 16);
#pragma unroll
        for (int rt = 0; rt < 4; ++rt)
#pragma unroll
            for (int ct = 0; ct < 4; ++ct)
                acc[rt][ct] = __builtin_amdgcn_mfma_f32_16x16x32_bf16(af[rt], bfv[ct], acc[rt][ct], 0, 0, 0);
        __syncthreads();                         // all waves done reading buf
    }

    const int col0 = wv * 64;
    float bcol[4];
#pragma unroll
    for (int ct = 0; ct < 4; ++ct) bcol[ct] = bias[col0 + ct * 16 + fr];
    const int mrow = (lane >> 4) * 4;

    if constexpr (POOL) {
        float cs[4] = {0.f, 0.f, 0.f, 0.f};
#pragma unroll
        for (int rt = 0; rt < 4; ++rt) {
#pragma unroll
            for (int e = 0; e < 4; ++e) {
                int m = row0 + rt * 16 + mrow + e;
                if (m < N_NODES) {
#pragma unroll
                    for (int ct = 0; ct < 4; ++ct)
                        cs[ct] += fmaxf(acc[rt][ct][e] + bcol[ct], 0.f);
                }
            }
        }
#pragma unroll
        for (int ct = 0; ct < 4; ++ct) {
            cs[ct] += __shfl_xor(cs[ct], 16);
            cs[ct] += __shfl_xor(cs[ct], 32);
        }
        if (lane < 16) {
#pragma unroll
            for (int ct = 0; ct < 4; ++ct)
                atomicAdd(&pooled[col0 + ct * 16 + lane], cs[ct]);
        }
    } else {
#pragma unroll
        for (int rt = 0; rt < 4; ++rt) {
#pragma unroll
            for (int e = 0; e < 4; ++e) {
                int m = row0 + rt * 16 + mrow + e;
                if (m < N_NODES) {
#pragma unroll
                    for (int ct = 0; ct < 4; ++ct) {
                        float v = fmaxf(acc[rt][ct][e] + bcol[ct], 0.f);
                        Xout[(size_t)m * HIDDEN + col0 + ct * 16 + fr] = enc1(v);
                    }
                }
            }
        }
    }
}

// ---------------- head MLP ----------------

__global__ void head_kernel(const float* __restrict__ pooled_sum, const float* __restrict__ cond,
                            const float* __restrict__ Wfc, const float* __restrict__ bfc,
                            const float* __restrict__ Wmean, const float* __restrict__ bmean,
                            const float* __restrict__ Wlogvar, const float* __restrict__ blogvar,
                            float* __restrict__ out) {
    __shared__ float v[HIDDEN + COND];
    __shared__ float h[LATENT];
    int t = threadIdx.x;
    if (t < HIDDEN) v[t] = pooled_sum[t] * (1.0f / N_NODES);
    if (t < COND) v[HIDDEN + t] = cond[t];
    __syncthreads();
    if (t < LATENT) {
        float s = bfc[t];
        for (int k = 0; k < HIDDEN + COND; ++k) s += v[k] * Wfc[k * LATENT + t];
        h[t] = fmaxf(s, 0.f);
    }
    __syncthreads();
    if (t < LATENT) {
        float s = bmean[t];
        for (int k = 0; k < LATENT; ++k) s += h[k] * Wmean[k * LATENT + t];
        out[t] = s;
    } else {
        int j = t - LATENT;
        float s = blogvar[j];
        for (int k = 0; k < LATENT; ++k) s += h[k] * Wlogvar[k * LATENT + j];
        out[LATENT + j] = s;
    }
}

// ---------------- launch ----------------

extern "C" void kernel_launch(void* const* d_in, const int* in_sizes, int n_in,
                              void* d_out, int out_size, void* d_ws, size_t ws_size,
                              hipStream_t stream) {
    const float* node_features = (const float*)d_in[0];
    const float* conditions    = (const float*)d_in[1];
    const int*   src           = (const int*)d_in[2];
    const int*   dst           = (const int*)d_in[3];
    const float* W1  = (const float*)d_in[4];
    const float* b1  = (const float*)d_in[5];
    const float* W2  = (const float*)d_in[6];
    const float* b2  = (const float*)d_in[7];
    const float* Wfc = (const float*)d_in[8];
    const float* bfc = (const float*)d_in[9];
    const float* Wmean   = (const float*)d_in[10];
    const float* bmean   = (const float*)d_in[11];
    const float* Wlogvar = (const float*)d_in[12];
    const float* blogvar = (const float*)d_in[13];
    float* out = (float*)d_out;

    size_t o = 0;
    auto alloc = [&](size_t bytes) {
        void* p = (char*)d_ws + o;
        o += (bytes + 255) & ~(size_t)255;
        return p;
    };
    int* deg       = (int*)alloc((size_t)N_NODES * 4);
    int* offsets   = (int*)alloc((size_t)(N_NODES + 1) * 4);
    int* incl      = (int*)alloc((size_t)N_NODES * 4);
    int* blocksums = (int*)alloc((size_t)SCAN_BLOCKS * 4);
    int* bcursor   = (int*)alloc((size_t)NB * 4);
    uint* pair_buf = (uint*)alloc((size_t)N_EDGES * 4);
    ushort* csr    = (ushort*)alloc((size_t)N_EDGES * 2);
    float* pooled  = (float*)alloc(HIDDEN * 4);
    ushort* Wst1   = (ushort*)alloc((size_t)HIDDEN * NODE_DIM * 2);
    ushort* Wst2   = (ushort*)alloc((size_t)HIDDEN * HIDDEN * 2);
    uchar* nf_fp8  = (uchar*)alloc((size_t)N_NODES * NODE_DIM);
    uchar* x1_fp8  = (uchar*)alloc((size_t)N_NODES * HIDDEN);
    // +64 rows pad: gemm staging reads past row 49999 (results masked)
    ushort* agg1   = (ushort*)alloc((size_t)(N_NODES + 64) * NODE_DIM * 2);
    ushort* agg2   = (ushort*)alloc((size_t)(N_NODES + 64) * HIDDEN * 2);

    prep_kernel<<<(PREP4 + 255) / 256, 256, 0, stream>>>(
        node_features, W1, W2, nf_fp8, Wst1, Wst2, deg, pooled);

    hist_kernel<<<N_EDGES / 256, 256, 0, stream>>>(dst, deg);
    scan_a_kernel<<<SCAN_BLOCKS, 256, 0, stream>>>(deg, incl, blocksums);
    scan_c_kernel<<<SCAN_BLOCKS, 256, 0, stream>>>(deg, incl, blocksums, offsets, bcursor);
    bucket_kernel<<<P1_GRID, 256, 0, stream>>>(src, dst, bcursor, pair_buf);
    csr_kernel<<<NB, 256, 0, stream>>>(pair_buf, offsets, csr);

    const int AGG_GRID  = (N_NODES * 64 + 255) / 256;
    const int GEMM_GRID = (N_NODES + 63) / 64;   // 782

    agg_kernel<NODE_DIM><<<AGG_GRID, 256, 0, stream>>>(nf_fp8, offsets, csr, agg1);
    gemm_lds_kernel<NODE_DIM, false><<<GEMM_GRID, 256, 0, stream>>>(agg1, Wst1, b1, x1_fp8, nullptr);

    agg_kernel<HIDDEN><<<AGG_GRID, 256, 0, stream>>>(x1_fp8, offsets, csr, agg2);
    gemm_lds_kernel<HIDDEN, true><<<GEMM_GRID, 256, 0, stream>>>(agg2, Wst2, b2, nullptr, pooled);

    head_kernel<<<1, 256, 0, stream>>>(pooled, conditions, Wfc, bfc,
                                       Wmean, bmean, Wlogvar, blogvar, out);
}

// Round 12
// 175.117 us; speedup vs baseline: 1.2572x; 1.0729x over previous
//
#include <hip/hip_runtime.h>

#define N_NODES   50000
#define N_EDGES   800000
#define NODE_DIM  128
#define HIDDEN    256
#define LATENT    128
#define COND      5

#define NB        196                          // buckets: dst>>8 (256-node ranges)
#define P1_CHUNK  4096
#define P1_GRID   ((N_EDGES + P1_CHUNK - 1) / P1_CHUNK)  // 196

typedef unsigned int uint;
typedef unsigned short ushort;
typedef unsigned char uchar;

typedef __attribute__((ext_vector_type(8))) short bf16x8;
typedef __attribute__((ext_vector_type(4))) float f32x4;

static __device__ __forceinline__ ushort f32_to_bf16(float f) {
    union { float f; uint u; } v; v.f = f;
    uint r = v.u + 0x7FFF + ((v.u >> 16) & 1);   // RNE
    return (ushort)(r >> 16);
}
static __device__ __forceinline__ uint pack_bf16(float lo, float hi) {
    return (uint)f32_to_bf16(lo) | ((uint)f32_to_bf16(hi) << 16);
}

// async global->LDS DMA, 16B per lane; LDS dest = wave-uniform base + lane*16
static __device__ __forceinline__ void gload_lds16(const void* g, void* l) {
    __builtin_amdgcn_global_load_lds(
        (const __attribute__((address_space(1))) unsigned int*)(unsigned long long)(uintptr_t)g,
        (__attribute__((address_space(3))) unsigned int*)(unsigned int)(uintptr_t)l,
        16, 0, 0);
}

// ---------------- fp8 e4m3 helpers (HW cvt with software fallback) ----------------

#if __has_builtin(__builtin_amdgcn_cvt_pk_f32_fp8) && __has_builtin(__builtin_amdgcn_cvt_pk_fp8_f32)
#define HW_FP8 1
#endif

#ifndef HW_FP8
static __device__ __forceinline__ float dec1_fp8(uint b) {
    uint sgn = b & 0x80, mag = b & 0x7f;
    float v;
    if (mag >= 8) {
        union { uint u; float f; } t;
        t.u = (((mag >> 3) + 120) << 23) | ((mag & 7) << 20);
        v = t.f;
    } else {
        v = (float)mag * 0.001953125f;   // 2^-9
    }
    return sgn ? -v : v;
}
static __device__ __forceinline__ uchar enc1_fp8(float f) {
    float a = fabsf(f);
    uint s = (f < 0.f) ? 0x80u : 0u;
    if (!(a >= 0.015625f)) {
        int q = (int)(a * 512.f + 0.5f);
        if (q > 7) q = 7;
        return (uchar)(s | (uint)q);
    }
    if (a >= 448.f) return (uchar)(s | 0x7E);
    union { float f; uint u; } t; t.f = a;
    uint e = (t.u >> 23) - 120;
    uint m = (t.u >> 20) & 7;
    uint rem = t.u & 0xFFFFF;
    uint v = (e << 3) | m;
    if (rem > 0x80000 || (rem == 0x80000 && (v & 1))) v++;
    if (v > 0x7E) v = 0x7E;
    return (uchar)(s | v);
}
#endif

static __device__ __forceinline__ void dec4_add(uint u, float* acc) {
#ifdef HW_FP8
    auto lo = __builtin_amdgcn_cvt_pk_f32_fp8((int)u, false);
    auto hi = __builtin_amdgcn_cvt_pk_f32_fp8((int)u, true);
    acc[0] += lo[0]; acc[1] += lo[1]; acc[2] += hi[0]; acc[3] += hi[1];
#else
    acc[0] += dec1_fp8(u & 0xff);
    acc[1] += dec1_fp8((u >> 8) & 0xff);
    acc[2] += dec1_fp8((u >> 16) & 0xff);
    acc[3] += dec1_fp8(u >> 24);
#endif
}
static __device__ __forceinline__ void dec2_add(uint u, float* acc) {
#ifdef HW_FP8
    auto lo = __builtin_amdgcn_cvt_pk_f32_fp8((int)u, false);
    acc[0] += lo[0]; acc[1] += lo[1];
#else
    acc[0] += dec1_fp8(u & 0xff);
    acc[1] += dec1_fp8((u >> 8) & 0xff);
#endif
}
static __device__ __forceinline__ uint enc2_fp8(float a, float b) {
#ifdef HW_FP8
    return (uint)__builtin_amdgcn_cvt_pk_fp8_f32(a, b, 0, false) & 0xFFFFu;
#else
    return (uint)enc1_fp8(a) | ((uint)enc1_fp8(b) << 8);
#endif
}
static __device__ __forceinline__ uchar enc1(float v) {
#ifdef HW_FP8
    return (uchar)(__builtin_amdgcn_cvt_pk_fp8_f32(v, v, 0, false) & 0xff);
#else
    return enc1_fp8(v);
#endif
}

// ---------------- prep: nf -> fp8, W -> DMA-packed bf16, zero pooled/bcount/bcursor2 ----------------
// Wst layout (ushort): [kstep][chunk w=kg*4+cc][col' 0..63][k' 0..7]
//   idx = (((k>>5)*16) + (((k&31)>>3)*4 + (c>>6)))*64*8 + (c&63)*8 + (k&7)

#define NF4   (N_NODES * NODE_DIM / 4)            // 1,600,000
#define PREP1 (NF4 + NODE_DIM * HIDDEN)           // + 32768
#define PREP2 (PREP1 + HIDDEN * HIDDEN)           // + 65536
#define PREP3 (PREP2 + HIDDEN)                    // + 256 (pooled zero)
#define PREP4 (PREP3 + NB)                        // + 196 (bcount zero)
#define PREP5 (PREP4 + NB)                        // + 196 (bcursor2 zero)

__global__ void prep_kernel(const float* __restrict__ nf,
                            const float* __restrict__ W1, const float* __restrict__ W2,
                            uchar* __restrict__ nf_fp8,
                            ushort* __restrict__ Wst1, ushort* __restrict__ Wst2,
                            float* __restrict__ pooled,
                            int* __restrict__ bcount, int* __restrict__ bcursor2) {
    int id = blockIdx.x * blockDim.x + threadIdx.x;
    if (id < NF4) {
        float4 v = reinterpret_cast<const float4*>(nf)[id];
        uint w = enc2_fp8(v.x, v.y) | (enc2_fp8(v.z, v.w) << 16);
        reinterpret_cast<uint*>(nf_fp8)[id] = w;
    } else if (id < PREP1) {
        int i = id - NF4;
        int k = i >> 8, c = i & 255;
        int idx = ((((k >> 5) * 16) + (((k & 31) >> 3) * 4 + (c >> 6))) * 64 + (c & 63)) * 8 + (k & 7);
        Wst1[idx] = f32_to_bf16(W1[i]);
    } else if (id < PREP2) {
        int i = id - PREP1;
        int k = i >> 8, c = i & 255;
        int idx = ((((k >> 5) * 16) + (((k & 31) >> 3) * 4 + (c >> 6))) * 64 + (c & 63)) * 8 + (k & 7);
        Wst2[idx] = f32_to_bf16(W2[i]);
    } else if (id < PREP3) {
        pooled[id - PREP2] = 0.f;
    } else if (id < PREP4) {
        bcount[id - PREP3] = 0;
    } else if (id < PREP5) {
        bcursor2[id - PREP4] = 0;
    }
}

// ---------------- CSR build v2: bucket count -> pair write -> per-bucket local CSR ----------------

__global__ __launch_bounds__(256) void bcount_kernel(const int* __restrict__ dst,
                                                     int* __restrict__ bcount) {
    __shared__ int cnt[NB];
    const int t = threadIdx.x;
    for (int i = t; i < NB; i += 256) cnt[i] = 0;
    __syncthreads();
    const int base = blockIdx.x * P1_CHUNK;
#pragma unroll
    for (int i = 0; i < 16; ++i) {
        int e = base + i * 256 + t;
        if (e < N_EDGES) atomicAdd(&cnt[dst[e] >> 8], 1);
    }
    __syncthreads();
    for (int i = t; i < NB; i += 256)
        if (cnt[i] > 0) atomicAdd(&bcount[i], cnt[i]);
}

// each block scans bucket counts in LDS (bases), then packs (src|dst<<16) bucket-contiguously
__global__ __launch_bounds__(256) void bwrite_kernel(const int* __restrict__ src,
                                                     const int* __restrict__ dst,
                                                     const int* __restrict__ bcount,
                                                     int* __restrict__ bcursor2,
                                                     uint* __restrict__ pair_buf) {
    __shared__ int s[256];
    __shared__ int cnt[NB];
    __shared__ int gbase[NB];
    const int t = threadIdx.x;
    s[t] = (t < NB) ? bcount[t] : 0;
    __syncthreads();
    for (int off = 1; off < 256; off <<= 1) {
        int v = (t >= off) ? s[t - off] : 0;
        __syncthreads();
        s[t] += v;
        __syncthreads();
    }
    for (int i = t; i < NB; i += 256) cnt[i] = 0;
    __syncthreads();

    const int base = blockIdx.x * P1_CHUNK;
    uint pk[16];
    int  bk[16], lr[16];
    bool ok[16];
#pragma unroll
    for (int i = 0; i < 16; ++i) {
        int e = base + i * 256 + t;
        ok[i] = e < N_EDGES;
        if (ok[i]) {
            int sv = src[e], d = dst[e];
            pk[i] = (uint)sv | ((uint)d << 16);
            bk[i] = d >> 8;
        }
    }
#pragma unroll
    for (int i = 0; i < 16; ++i)
        if (ok[i]) lr[i] = atomicAdd(&cnt[bk[i]], 1);
    __syncthreads();
    if (t < NB) {
        int c = cnt[t];
        if (c > 0) gbase[t] = ((t > 0) ? s[t - 1] : 0) + atomicAdd(&bcursor2[t], c);
    }
    __syncthreads();
#pragma unroll
    for (int i = 0; i < 16; ++i)
        if (ok[i]) pair_buf[gbase[bk[i]] + lr[i]] = pk[i];
}

// one block per bucket: local degree count -> local scan -> offsets + local scatter
__global__ __launch_bounds__(256) void csrloc_kernel(const uint* __restrict__ pair_buf,
                                                     const int* __restrict__ bcount,
                                                     int* __restrict__ offsets,
                                                     ushort* __restrict__ csr) {
    __shared__ int s[256];
    __shared__ int lcnt[256];
    __shared__ int loff[256];
    __shared__ int lcur[256];
    const int t = threadIdx.x;
    const int b = blockIdx.x;
    s[t] = (t < NB) ? bcount[t] : 0;
    __syncthreads();
    for (int off = 1; off < 256; off <<= 1) {
        int v = (t >= off) ? s[t - off] : 0;
        __syncthreads();
        s[t] += v;
        __syncthreads();
    }
    const int e0 = (b > 0) ? s[b - 1] : 0;
    const int e1 = s[b];
    lcnt[t] = 0;
    lcur[t] = 0;
    __syncthreads();

    for (int j = e0 + t; j < e1; j += 256)
        atomicAdd(&lcnt[(pair_buf[j] >> 16) & 255], 1);
    __syncthreads();

    const int myc = lcnt[t];
    s[t] = myc;
    __syncthreads();
    for (int off = 1; off < 256; off <<= 1) {
        int v = (t >= off) ? s[t - off] : 0;
        __syncthreads();
        s[t] += v;
        __syncthreads();
    }
    const int lofft = s[t] - myc;   // exclusive
    loff[t] = lofft;
    const int node = (b << 8) + t;
    if (node < N_NODES) offsets[node] = e0 + lofft;
    if (b == 0 && t == 0) offsets[N_NODES] = N_EDGES;
    __syncthreads();

    for (int j = e0 + t; j < e1; j += 256) {
        uint p = pair_buf[j];
        int dl = (int)(p >> 16) & 255;
        int r = atomicAdd(&lcur[dl], 1);
        csr[e0 + loff[dl] + r] = (ushort)(p & 0xFFFFu);
    }
}

// ---------------- aggregation: wave per node, fp8 gather, 16-deep load pipeline ----------------

template <int D>
__global__ __launch_bounds__(256) void agg_kernel(const uchar* __restrict__ x,
                                                  const int* __restrict__ offsets,
                                                  const ushort* __restrict__ csr,
                                                  ushort* __restrict__ out) {
    constexpr int BPL = D / 64;   // bytes per lane: 2 or 4
    int node = (blockIdx.x * blockDim.x + threadIdx.x) >> 6;
    int lane = threadIdx.x & 63;
    if (node >= N_NODES) return;
    int j0 = __builtin_amdgcn_readfirstlane(offsets[node]);
    int j1 = __builtin_amdgcn_readfirstlane(offsets[node + 1]);

    float acc[BPL];
#pragma unroll
    for (int i = 0; i < BPL; ++i) acc[i] = 0.f;

    const uchar* base = x + lane * BPL;
    const int il = lane & 15;

    int idxv = (j0 + il < j1) ? (int)csr[j0 + il] : 0;

    for (int jb = j0; jb < j1; jb += 16) {
        int idxn = (jb + 16 + il < j1) ? (int)csr[jb + 16 + il] : 0;
        int n = j1 - jb; n = (n > 16) ? 16 : n;
        uint u[16];
        if (n == 16) {
#pragma unroll
            for (int i = 0; i < 16; ++i) {
                int s = __shfl(idxv, i);
                if constexpr (BPL == 4)
                    u[i] = *reinterpret_cast<const uint*>(base + (size_t)s * D);
                else
                    u[i] = *reinterpret_cast<const ushort*>(base + (size_t)s * D);
            }
#pragma unroll
            for (int i = 0; i < 16; ++i) {
                if constexpr (BPL == 4) dec4_add(u[i], acc); else dec2_add(u[i], acc);
            }
        } else {
#pragma unroll
            for (int i = 0; i < 16; ++i) {
                if (i < n) {
                    int s = __shfl(idxv, i);
                    if constexpr (BPL == 4)
                        u[i] = *reinterpret_cast<const uint*>(base + (size_t)s * D);
                    else
                        u[i] = *reinterpret_cast<const ushort*>(base + (size_t)s * D);
                }
            }
#pragma unroll
            for (int i = 0; i < 16; ++i) {
                if (i < n) {
                    if constexpr (BPL == 4) dec4_add(u[i], acc); else dec2_add(u[i], acc);
                }
            }
        }
        idxv = idxn;
    }

    if constexpr (BPL == 4) {
        uint2 o;
        o.x = pack_bf16(acc[0], acc[1]);
        o.y = pack_bf16(acc[2], acc[3]);
        *reinterpret_cast<uint2*>(out + (size_t)node * D + lane * 4) = o;
    } else {
        *reinterpret_cast<uint*>(out + (size_t)node * D + lane * 2) = pack_bf16(acc[0], acc[1]);
    }
}

// ---------------- MFMA GEMM v5: 32-row blocks, coalesced LDS-staged DMA ----------------
// block = 32 rows x 256 cols (grid 1563), 4 waves; wave = 32x64 (2x4 fragments).
// BK=32, double-buffered LDS (2 x 18KB = 36KB -> 4 blocks/CU).
// LDS per buffer: A chunks rt(0..1) @ rt*1024: [row' 0..15][kgroup 0..3][16B];
//                 W chunks w(0..15)  @ 2048+w*1024 (packed Wst, contiguous 1KB DMA).
// Fragment reads: af[rt] @ rt*1024 + fr*64 + kgl*16;
//                 bfv[ct] @ 2048 + (kgl*4+wv)*1024 + (ct*16+fr)*16.

template <int K, bool POOL>
__global__ __launch_bounds__(256) void gemm_lds_kernel(const ushort* __restrict__ A,
                                                       const ushort* __restrict__ Wst,
                                                       const float* __restrict__ bias,
                                                       uchar* __restrict__ Xout,
                                                       float* __restrict__ pooled) {
    constexpr int BUFB  = 18432;
    constexpr int NSTEP = K / 32;
    __shared__ uchar lds_raw[2 * BUFB];

    const int t    = threadIdx.x;
    const int lane = t & 63;
    const int wv   = t >> 6;
    const int row0 = blockIdx.x * 32;
    const int fr   = lane & 15;
    const int kgl  = lane >> 4;

    auto stage = [&](int buf, int ks) {
#pragma unroll
        for (int j = 0; j < 5; ++j) {
            const int c = wv * 5 + j;           // 0..19, wave-uniform; 18 used
            if (c < 2) {
                gload_lds16(A + (size_t)(row0 + c * 16 + (lane >> 2)) * K + ks * 32 + (lane & 3) * 8,
                            &lds_raw[buf * BUFB + c * 1024]);
            } else if (c < 18) {
                const int w = c - 2;            // 0..15
                gload_lds16(Wst + ((size_t)ks * 16 + w) * 512 + lane * 8,
                            &lds_raw[buf * BUFB + 2048 + w * 1024]);
            }
        }
    };

    f32x4 acc[2][4];
#pragma unroll
    for (int rt = 0; rt < 2; ++rt)
#pragma unroll
        for (int ct = 0; ct < 4; ++ct)
            acc[rt][ct] = (f32x4){0.f, 0.f, 0.f, 0.f};

    stage(0, 0);
#pragma unroll
    for (int ks = 0; ks < NSTEP; ++ks) {
        const int buf = ks & 1;
        if (ks + 1 < NSTEP) stage(buf ^ 1, ks + 1);
        __syncthreads();                         // drains vmcnt -> buf ready
        const uchar* bb = &lds_raw[buf * BUFB];
        bf16x8 af[2], bfv[4];
#pragma unroll
        for (int rt = 0; rt < 2; ++rt)
            af[rt] = *reinterpret_cast<const bf16x8*>(bb + rt * 1024 + fr * 64 + kgl * 16);
#pragma unroll
        for (int ct = 0; ct < 4; ++ct)
            bfv[ct] = *reinterpret_cast<const bf16x8*>(bb + 2048 + (kgl * 4 + wv) * 1024 + (ct * 16 + fr) * 16);
#pragma unroll
        for (int rt = 0; rt < 2; ++rt)
#pragma unroll
            for (int ct = 0; ct < 4; ++ct)
                acc[rt][ct] = __builtin_amdgcn_mfma_f32_16x16x32_bf16(af[rt], bfv[ct], acc[rt][ct], 0, 0, 0);
        __syncthreads();                         // all waves done reading buf
    }

    const int col0 = wv * 64;
    float bcol[4];
#pragma unroll
    for (int ct = 0; ct < 4; ++ct) bcol[ct] = bias[col0 + ct * 16 + fr];
    const int mrow = (lane >> 4) * 4;

    if constexpr (POOL) {
        float cs[4] = {0.f, 0.f, 0.f, 0.f};
#pragma unroll
        for (int rt = 0; rt < 2; ++rt) {
#pragma unroll
            for (int e = 0; e < 4; ++e) {
                int m = row0 + rt * 16 + mrow + e;
                if (m < N_NODES) {
#pragma unroll
                    for (int ct = 0; ct < 4; ++ct)
                        cs[ct] += fmaxf(acc[rt][ct][e] + bcol[ct], 0.f);
                }
            }
        }
#pragma unroll
        for (int ct = 0; ct < 4; ++ct) {
            cs[ct] += __shfl_xor(cs[ct], 16);
            cs[ct] += __shfl_xor(cs[ct], 32);
        }
        if (lane < 16) {
#pragma unroll
            for (int ct = 0; ct < 4; ++ct)
                atomicAdd(&pooled[col0 + ct * 16 + lane], cs[ct]);
        }
    } else {
#pragma unroll
        for (int rt = 0; rt < 2; ++rt) {
#pragma unroll
            for (int e = 0; e < 4; ++e) {
                int m = row0 + rt * 16 + mrow + e;
                if (m < N_NODES) {
#pragma unroll
                    for (int ct = 0; ct < 4; ++ct) {
                        float v = fmaxf(acc[rt][ct][e] + bcol[ct], 0.f);
                        Xout[(size_t)m * HIDDEN + col0 + ct * 16 + fr] = enc1(v);
                    }
                }
            }
        }
    }
}

// ---------------- head MLP ----------------

__global__ void head_kernel(const float* __restrict__ pooled_sum, const float* __restrict__ cond,
                            const float* __restrict__ Wfc, const float* __restrict__ bfc,
                            const float* __restrict__ Wmean, const float* __restrict__ bmean,
                            const float* __restrict__ Wlogvar, const float* __restrict__ blogvar,
                            float* __restrict__ out) {
    __shared__ float v[HIDDEN + COND];
    __shared__ float h[LATENT];
    int t = threadIdx.x;
    if (t < HIDDEN) v[t] = pooled_sum[t] * (1.0f / N_NODES);
    if (t < COND) v[HIDDEN + t] = cond[t];
    __syncthreads();
    if (t < LATENT) {
        float s = bfc[t];
        for (int k = 0; k < HIDDEN + COND; ++k) s += v[k] * Wfc[k * LATENT + t];
        h[t] = fmaxf(s, 0.f);
    }
    __syncthreads();
    if (t < LATENT) {
        float s = bmean[t];
        for (int k = 0; k < LATENT; ++k) s += h[k] * Wmean[k * LATENT + t];
        out[t] = s;
    } else {
        int j = t - LATENT;
        float s = blogvar[j];
        for (int k = 0; k < LATENT; ++k) s += h[k] * Wlogvar[k * LATENT + j];
        out[LATENT + j] = s;
    }
}

// ---------------- launch ----------------

extern "C" void kernel_launch(void* const* d_in, const int* in_sizes, int n_in,
                              void* d_out, int out_size, void* d_ws, size_t ws_size,
                              hipStream_t stream) {
    const float* node_features = (const float*)d_in[0];
    const float* conditions    = (const float*)d_in[1];
    const int*   src           = (const int*)d_in[2];
    const int*   dst           = (const int*)d_in[3];
    const float* W1  = (const float*)d_in[4];
    const float* b1  = (const float*)d_in[5];
    const float* W2  = (const float*)d_in[6];
    const float* b2  = (const float*)d_in[7];
    const float* Wfc = (const float*)d_in[8];
    const float* bfc = (const float*)d_in[9];
    const float* Wmean   = (const float*)d_in[10];
    const float* bmean   = (const float*)d_in[11];
    const float* Wlogvar = (const float*)d_in[12];
    const float* blogvar = (const float*)d_in[13];
    float* out = (float*)d_out;

    size_t o = 0;
    auto alloc = [&](size_t bytes) {
        void* p = (char*)d_ws + o;
        o += (bytes + 255) & ~(size_t)255;
        return p;
    };
    int* offsets   = (int*)alloc((size_t)(N_NODES + 1) * 4);
    int* bcount    = (int*)alloc((size_t)NB * 4);
    int* bcursor2  = (int*)alloc((size_t)NB * 4);
    uint* pair_buf = (uint*)alloc((size_t)N_EDGES * 4);
    ushort* csr    = (ushort*)alloc((size_t)N_EDGES * 2);
    float* pooled  = (float*)alloc(HIDDEN * 4);
    ushort* Wst1   = (ushort*)alloc((size_t)HIDDEN * NODE_DIM * 2);
    ushort* Wst2   = (ushort*)alloc((size_t)HIDDEN * HIDDEN * 2);
    uchar* nf_fp8  = (uchar*)alloc((size_t)N_NODES * NODE_DIM);
    uchar* x1_fp8  = (uchar*)alloc((size_t)N_NODES * HIDDEN);
    // +64 rows pad: gemm staging reads past row 49999 (results masked)
    ushort* agg1   = (ushort*)alloc((size_t)(N_NODES + 64) * NODE_DIM * 2);
    ushort* agg2   = (ushort*)alloc((size_t)(N_NODES + 64) * HIDDEN * 2);

    prep_kernel<<<(PREP5 + 255) / 256, 256, 0, stream>>>(
        node_features, W1, W2, nf_fp8, Wst1, Wst2, pooled, bcount, bcursor2);

    bcount_kernel<<<P1_GRID, 256, 0, stream>>>(dst, bcount);
    bwrite_kernel<<<P1_GRID, 256, 0, stream>>>(src, dst, bcount, bcursor2, pair_buf);
    csrloc_kernel<<<NB, 256, 0, stream>>>(pair_buf, bcount, offsets, csr);

    const int AGG_GRID  = (N_NODES * 64 + 255) / 256;
    const int GEMM_GRID = (N_NODES + 31) / 32;   // 1563

    agg_kernel<NODE_DIM><<<AGG_GRID, 256, 0, stream>>>(nf_fp8, offsets, csr, agg1);
    gemm_lds_kernel<NODE_DIM, false><<<GEMM_GRID, 256, 0, stream>>>(agg1, Wst1, b1, x1_fp8, nullptr);

    agg_kernel<HIDDEN><<<AGG_GRID, 256, 0, stream>>>(x1_fp8, offsets, csr, agg2);
    gemm_lds_kernel<HIDDEN, true><<<GEMM_GRID, 256, 0, stream>>>(agg2, Wst2, b2, nullptr, pooled);

    head_kernel<<<1, 256, 0, stream>>>(pooled, conditions, Wfc, bfc,
                                       Wmean, bmean, Wlogvar, blogvar, out);
}

// Round 13
// 142.618 us; speedup vs baseline: 1.5437x; 1.2279x over previous
//
#include <hip/hip_runtime.h>

#define N_NODES   50000
#define N_EDGES   800000
#define NODE_DIM  128
#define HIDDEN    256
#define LATENT    128
#define COND      5

#define NB        196                          // buckets: dst>>8 (256-node ranges)
#define P1_CHUNK  4096
#define P1_GRID   ((N_EDGES + P1_CHUNK - 1) / P1_CHUNK)  // 196

typedef unsigned int uint;
typedef unsigned short ushort;
typedef unsigned char uchar;

typedef __attribute__((ext_vector_type(8))) short bf16x8;
typedef __attribute__((ext_vector_type(4))) float f32x4;

static __device__ __forceinline__ ushort f32_to_bf16(float f) {
    union { float f; uint u; } v; v.f = f;
    uint r = v.u + 0x7FFF + ((v.u >> 16) & 1);   // RNE
    return (ushort)(r >> 16);
}
static __device__ __forceinline__ uint pack_bf16(float lo, float hi) {
    return (uint)f32_to_bf16(lo) | ((uint)f32_to_bf16(hi) << 16);
}

// async global->LDS DMA, 16B per lane; LDS dest = wave-uniform base + lane*16
static __device__ __forceinline__ void gload_lds16(const void* g, void* l) {
    __builtin_amdgcn_global_load_lds(
        (const __attribute__((address_space(1))) unsigned int*)(unsigned long long)(uintptr_t)g,
        (__attribute__((address_space(3))) unsigned int*)(unsigned int)(uintptr_t)l,
        16, 0, 0);
}

// ---------------- fp8 e4m3 helpers (HW cvt with software fallback) ----------------

#if __has_builtin(__builtin_amdgcn_cvt_pk_f32_fp8) && __has_builtin(__builtin_amdgcn_cvt_pk_fp8_f32)
#define HW_FP8 1
#endif

#ifndef HW_FP8
static __device__ __forceinline__ float dec1_fp8(uint b) {
    uint sgn = b & 0x80, mag = b & 0x7f;
    float v;
    if (mag >= 8) {
        union { uint u; float f; } t;
        t.u = (((mag >> 3) + 120) << 23) | ((mag & 7) << 20);
        v = t.f;
    } else {
        v = (float)mag * 0.001953125f;   // 2^-9
    }
    return sgn ? -v : v;
}
static __device__ __forceinline__ uchar enc1_fp8(float f) {
    float a = fabsf(f);
    uint s = (f < 0.f) ? 0x80u : 0u;
    if (!(a >= 0.015625f)) {
        int q = (int)(a * 512.f + 0.5f);
        if (q > 7) q = 7;
        return (uchar)(s | (uint)q);
    }
    if (a >= 448.f) return (uchar)(s | 0x7E);
    union { float f; uint u; } t; t.f = a;
    uint e = (t.u >> 23) - 120;
    uint m = (t.u >> 20) & 7;
    uint rem = t.u & 0xFFFFF;
    uint v = (e << 3) | m;
    if (rem > 0x80000 || (rem == 0x80000 && (v & 1))) v++;
    if (v > 0x7E) v = 0x7E;
    return (uchar)(s | v);
}
#endif

static __device__ __forceinline__ void dec4_add(uint u, float* acc) {
#ifdef HW_FP8
    auto lo = __builtin_amdgcn_cvt_pk_f32_fp8((int)u, false);
    auto hi = __builtin_amdgcn_cvt_pk_f32_fp8((int)u, true);
    acc[0] += lo[0]; acc[1] += lo[1]; acc[2] += hi[0]; acc[3] += hi[1];
#else
    acc[0] += dec1_fp8(u & 0xff);
    acc[1] += dec1_fp8((u >> 8) & 0xff);
    acc[2] += dec1_fp8((u >> 16) & 0xff);
    acc[3] += dec1_fp8(u >> 24);
#endif
}
static __device__ __forceinline__ void dec2_add(uint u, float* acc) {
#ifdef HW_FP8
    auto lo = __builtin_amdgcn_cvt_pk_f32_fp8((int)u, false);
    acc[0] += lo[0]; acc[1] += lo[1];
#else
    acc[0] += dec1_fp8(u & 0xff);
    acc[1] += dec1_fp8((u >> 8) & 0xff);
#endif
}
static __device__ __forceinline__ uint enc2_fp8(float a, float b) {
#ifdef HW_FP8
    return (uint)__builtin_amdgcn_cvt_pk_fp8_f32(a, b, 0, false) & 0xFFFFu;
#else
    return (uint)enc1_fp8(a) | ((uint)enc1_fp8(b) << 8);
#endif
}
static __device__ __forceinline__ uchar enc1(float v) {
#ifdef HW_FP8
    return (uchar)(__builtin_amdgcn_cvt_pk_fp8_f32(v, v, 0, false) & 0xff);
#else
    return enc1_fp8(v);
#endif
}

// ---------------- prep: nf -> fp8, W -> DMA-packed bf16, zero pooled/bcount/bcursor2 ----------------
// Wst layout (ushort): [kstep][chunk w=kg*4+cc][col' 0..63][k' 0..7]
//   idx = (((k>>5)*16) + (((k&31)>>3)*4 + (c>>6)))*64*8 + (c&63)*8 + (k&7)

#define NF4   (N_NODES * NODE_DIM / 4)            // 1,600,000
#define PREP1 (NF4 + NODE_DIM * HIDDEN)           // + 32768
#define PREP2 (PREP1 + HIDDEN * HIDDEN)           // + 65536
#define PREP3 (PREP2 + HIDDEN)                    // + 256 (pooled zero)
#define PREP4 (PREP3 + NB)                        // + 196 (bcount zero)
#define PREP5 (PREP4 + NB)                        // + 196 (bcursor2 zero)

__global__ void prep_kernel(const float* __restrict__ nf,
                            const float* __restrict__ W1, const float* __restrict__ W2,
                            uchar* __restrict__ nf_fp8,
                            ushort* __restrict__ Wst1, ushort* __restrict__ Wst2,
                            float* __restrict__ pooled,
                            int* __restrict__ bcount, int* __restrict__ bcursor2) {
    int id = blockIdx.x * blockDim.x + threadIdx.x;
    if (id < NF4) {
        float4 v = reinterpret_cast<const float4*>(nf)[id];
        uint w = enc2_fp8(v.x, v.y) | (enc2_fp8(v.z, v.w) << 16);
        reinterpret_cast<uint*>(nf_fp8)[id] = w;
    } else if (id < PREP1) {
        int i = id - NF4;
        int k = i >> 8, c = i & 255;
        int idx = ((((k >> 5) * 16) + (((k & 31) >> 3) * 4 + (c >> 6))) * 64 + (c & 63)) * 8 + (k & 7);
        Wst1[idx] = f32_to_bf16(W1[i]);
    } else if (id < PREP2) {
        int i = id - PREP1;
        int k = i >> 8, c = i & 255;
        int idx = ((((k >> 5) * 16) + (((k & 31) >> 3) * 4 + (c >> 6))) * 64 + (c & 63)) * 8 + (k & 7);
        Wst2[idx] = f32_to_bf16(W2[i]);
    } else if (id < PREP3) {
        pooled[id - PREP2] = 0.f;
    } else if (id < PREP4) {
        bcount[id - PREP3] = 0;
    } else if (id < PREP5) {
        bcursor2[id - PREP4] = 0;
    }
}

// ---------------- CSR build: bucket count -> pair write -> per-bucket local CSR ----------------

__global__ __launch_bounds__(256) void bcount_kernel(const int* __restrict__ dst,
                                                     int* __restrict__ bcount) {
    __shared__ int cnt[NB];
    const int t = threadIdx.x;
    for (int i = t; i < NB; i += 256) cnt[i] = 0;
    __syncthreads();
    const int base = blockIdx.x * P1_CHUNK;
#pragma unroll
    for (int i = 0; i < 16; ++i) {
        int e = base + i * 256 + t;
        if (e < N_EDGES) atomicAdd(&cnt[dst[e] >> 8], 1);
    }
    __syncthreads();
    for (int i = t; i < NB; i += 256)
        if (cnt[i] > 0) atomicAdd(&bcount[i], cnt[i]);
}

__global__ __launch_bounds__(256) void bwrite_kernel(const int* __restrict__ src,
                                                     const int* __restrict__ dst,
                                                     const int* __restrict__ bcount,
                                                     int* __restrict__ bcursor2,
                                                     uint* __restrict__ pair_buf) {
    __shared__ int s[256];
    __shared__ int cnt[NB];
    __shared__ int gbase[NB];
    const int t = threadIdx.x;
    s[t] = (t < NB) ? bcount[t] : 0;
    __syncthreads();
    for (int off = 1; off < 256; off <<= 1) {
        int v = (t >= off) ? s[t - off] : 0;
        __syncthreads();
        s[t] += v;
        __syncthreads();
    }
    for (int i = t; i < NB; i += 256) cnt[i] = 0;
    __syncthreads();

    const int base = blockIdx.x * P1_CHUNK;
    uint pk[16];
    int  bk[16], lr[16];
    bool ok[16];
#pragma unroll
    for (int i = 0; i < 16; ++i) {
        int e = base + i * 256 + t;
        ok[i] = e < N_EDGES;
        if (ok[i]) {
            int sv = src[e], d = dst[e];
            pk[i] = (uint)sv | ((uint)d << 16);
            bk[i] = d >> 8;
        }
    }
#pragma unroll
    for (int i = 0; i < 16; ++i)
        if (ok[i]) lr[i] = atomicAdd(&cnt[bk[i]], 1);
    __syncthreads();
    if (t < NB) {
        int c = cnt[t];
        if (c > 0) gbase[t] = ((t > 0) ? s[t - 1] : 0) + atomicAdd(&bcursor2[t], c);
    }
    __syncthreads();
#pragma unroll
    for (int i = 0; i < 16; ++i)
        if (ok[i]) pair_buf[gbase[bk[i]] + lr[i]] = pk[i];
}

__global__ __launch_bounds__(256) void csrloc_kernel(const uint* __restrict__ pair_buf,
                                                     const int* __restrict__ bcount,
                                                     int* __restrict__ offsets,
                                                     ushort* __restrict__ csr) {
    __shared__ int s[256];
    __shared__ int lcnt[256];
    __shared__ int loff[256];
    __shared__ int lcur[256];
    const int t = threadIdx.x;
    const int b = blockIdx.x;
    s[t] = (t < NB) ? bcount[t] : 0;
    __syncthreads();
    for (int off = 1; off < 256; off <<= 1) {
        int v = (t >= off) ? s[t - off] : 0;
        __syncthreads();
        s[t] += v;
        __syncthreads();
    }
    const int e0 = (b > 0) ? s[b - 1] : 0;
    const int e1 = s[b];
    lcnt[t] = 0;
    lcur[t] = 0;
    __syncthreads();

    for (int j = e0 + t; j < e1; j += 256)
        atomicAdd(&lcnt[(pair_buf[j] >> 16) & 255], 1);
    __syncthreads();

    const int myc = lcnt[t];
    s[t] = myc;
    __syncthreads();
    for (int off = 1; off < 256; off <<= 1) {
        int v = (t >= off) ? s[t - off] : 0;
        __syncthreads();
        s[t] += v;
        __syncthreads();
    }
    const int lofft = s[t] - myc;   // exclusive
    loff[t] = lofft;
    const int node = (b << 8) + t;
    if (node < N_NODES) offsets[node] = e0 + lofft;
    if (b == 0 && t == 0) offsets[N_NODES] = N_EDGES;
    __syncthreads();

    for (int j = e0 + t; j < e1; j += 256) {
        uint p = pair_buf[j];
        int dl = (int)(p >> 16) & 255;
        int r = atomicAdd(&lcur[dl], 1);
        csr[e0 + loff[dl] + r] = (ushort)(p & 0xFFFFu);
    }
}

// ---------------- aggregation: wave per node, fp8 gather, 16-deep load pipeline ----------------

template <int D>
__global__ __launch_bounds__(256) void agg_kernel(const uchar* __restrict__ x,
                                                  const int* __restrict__ offsets,
                                                  const ushort* __restrict__ csr,
                                                  ushort* __restrict__ out) {
    constexpr int BPL = D / 64;   // bytes per lane: 2 or 4
    int node = (blockIdx.x * blockDim.x + threadIdx.x) >> 6;
    int lane = threadIdx.x & 63;
    if (node >= N_NODES) return;
    int j0 = __builtin_amdgcn_readfirstlane(offsets[node]);
    int j1 = __builtin_amdgcn_readfirstlane(offsets[node + 1]);

    float acc[BPL];
#pragma unroll
    for (int i = 0; i < BPL; ++i) acc[i] = 0.f;

    const uchar* base = x + lane * BPL;
    const int il = lane & 15;

    int idxv = (j0 + il < j1) ? (int)csr[j0 + il] : 0;

    for (int jb = j0; jb < j1; jb += 16) {
        int idxn = (jb + 16 + il < j1) ? (int)csr[jb + 16 + il] : 0;
        int n = j1 - jb; n = (n > 16) ? 16 : n;
        uint u[16];
        if (n == 16) {
#pragma unroll
            for (int i = 0; i < 16; ++i) {
                int s = __shfl(idxv, i);
                if constexpr (BPL == 4)
                    u[i] = *reinterpret_cast<const uint*>(base + (size_t)s * D);
                else
                    u[i] = *reinterpret_cast<const ushort*>(base + (size_t)s * D);
            }
#pragma unroll
            for (int i = 0; i < 16; ++i) {
                if constexpr (BPL == 4) dec4_add(u[i], acc); else dec2_add(u[i], acc);
            }
        } else {
#pragma unroll
            for (int i = 0; i < 16; ++i) {
                if (i < n) {
                    int s = __shfl(idxv, i);
                    if constexpr (BPL == 4)
                        u[i] = *reinterpret_cast<const uint*>(base + (size_t)s * D);
                    else
                        u[i] = *reinterpret_cast<const ushort*>(base + (size_t)s * D);
                }
            }
#pragma unroll
            for (int i = 0; i < 16; ++i) {
                if (i < n) {
                    if constexpr (BPL == 4) dec4_add(u[i], acc); else dec2_add(u[i], acc);
                }
            }
        }
        idxv = idxn;
    }

    if constexpr (BPL == 4) {
        uint2 o;
        o.x = pack_bf16(acc[0], acc[1]);
        o.y = pack_bf16(acc[2], acc[3]);
        *reinterpret_cast<uint2*>(out + (size_t)node * D + lane * 4) = o;
    } else {
        *reinterpret_cast<uint*>(out + (size_t)node * D + lane * 2) = pack_bf16(acc[0], acc[1]);
    }
}

// ---------------- MFMA GEMM v6: persistent blocks, W resident in LDS ----------------
// block = 256 threads (4 waves) = 64 rows x 128 cols; colhalf = blockIdx&1.
// wave wv: rows (wv&1)*32.., cols (wv>>1)*64.. -> 2x4 fragments (same as v5).
// LDS: [0, WB): W half (loaded ONCE, packed Wst chunks);
//      [WB + buf*AB, +AB): A tile (64 rows x K), double-buffered.
// A chunk c (1KB): ks=c>>2, rt=c&3; lane l holds row rt*16+(l>>2),
//   kgroup (l&3)^((l>>3)&3) -> 4-lane quads read full 64B lines (coalesced)
//   and fragment reads are 2-way-bank (free): addr fr*64 + (kgl^((fr>>1)&3))*16.
// Loop: stage A[t+1] -> compute[t] -> epilogue -> barrier (drain covered by compute).

template <int K, bool POOL>
__global__ __launch_bounds__(256) void gemm_res_kernel(const ushort* __restrict__ A,
                                                       const ushort* __restrict__ Wst,
                                                       const float* __restrict__ bias,
                                                       uchar* __restrict__ Xout,
                                                       float* __restrict__ pooled,
                                                       int nblk) {
    constexpr int NSTEP = K / 32;
    constexpr int WB    = NSTEP * 8 * 1024;    // W half bytes (64KB / 32KB)
    constexpr int AB    = NSTEP * 4 * 1024;    // A tile bytes (32KB / 16KB)
    constexpr int NT    = (N_NODES + 63) / 64; // 782 row-tiles
    __shared__ uchar lds[WB + 2 * AB];

    const int t    = threadIdx.x;
    const int lane = t & 63;
    const int wv   = t >> 6;
    const int fr   = lane & 15;
    const int kgl  = lane >> 4;
    const int colhalf = blockIdx.x & 1;
    const int stride  = nblk >> 1;

    const int kx = (lane & 3) ^ ((lane >> 3) & 3);   // A source k-group swizzle

    // ---- W load (once) ----
#pragma unroll
    for (int j = 0; j < NSTEP * 2; ++j) {
        const int lc = wv * (NSTEP * 2) + j;         // wave-uniform
        const int ks = lc >> 3, r = lc & 7;
        const int kg = r >> 1, ccl = r & 1;
        gload_lds16(Wst + ((size_t)ks * 16 + kg * 4 + colhalf * 2 + ccl) * 512 + lane * 8,
                    &lds[lc * 1024]);
    }

    auto stageA = [&](int buf, int row0) {
#pragma unroll
        for (int j = 0; j < NSTEP; ++j) {
            const int c  = wv * NSTEP + j;           // wave-uniform, 0..4*NSTEP-1
            const int ks = c >> 2, rt = c & 3;
            gload_lds16(A + (size_t)(row0 + rt * 16 + (lane >> 2)) * K + ks * 32 + kx * 8,
                        &lds[WB + buf * AB + c * 1024]);
        }
    };

    const int rowsel = (wv & 1) * 2;       // rt-chunk base for this wave
    const int colsel = wv >> 1;            // 64-col slab within the 128-col half
    const int col0   = colhalf * 128 + colsel * 64;
    float bcol[4];
#pragma unroll
    for (int ct = 0; ct < 4; ++ct) bcol[ct] = bias[col0 + ct * 16 + fr];
    const int mrow = kgl * 4;
    const int aswz = (kgl ^ ((fr >> 1) & 3)) * 16;

    float cs[4] = {0.f, 0.f, 0.f, 0.f};

    int tile = blockIdx.x >> 1;
    stageA(0, tile * 64);
    __syncthreads();                        // drains W + first A

    for (int buf = 0; tile < NT; tile += stride, buf ^= 1) {
        const int tn = tile + stride;
        if (tn < NT) stageA(buf ^ 1, tn * 64);

        f32x4 acc[2][4];
#pragma unroll
        for (int rt = 0; rt < 2; ++rt)
#pragma unroll
            for (int ct = 0; ct < 4; ++ct)
                acc[rt][ct] = (f32x4){0.f, 0.f, 0.f, 0.f};

        const uchar* ab = &lds[WB + buf * AB];
#pragma unroll
        for (int ks = 0; ks < NSTEP; ++ks) {
            bf16x8 af[2], bfv[4];
#pragma unroll
            for (int rt = 0; rt < 2; ++rt)
                af[rt] = *reinterpret_cast<const bf16x8*>(ab + (ks * 4 + rowsel + rt) * 1024 + fr * 64 + aswz);
#pragma unroll
            for (int ct = 0; ct < 4; ++ct)
                bfv[ct] = *reinterpret_cast<const bf16x8*>(&lds[(ks * 8 + kgl * 2 + colsel) * 1024 + (ct * 16 + fr) * 16]);
#pragma unroll
            for (int rt = 0; rt < 2; ++rt)
#pragma unroll
                for (int ct = 0; ct < 4; ++ct)
                    acc[rt][ct] = __builtin_amdgcn_mfma_f32_16x16x32_bf16(af[rt], bfv[ct], acc[rt][ct], 0, 0, 0);
        }

        const int rowbase = tile * 64 + (wv & 1) * 32;
        if constexpr (POOL) {
#pragma unroll
            for (int rt = 0; rt < 2; ++rt) {
#pragma unroll
                for (int e = 0; e < 4; ++e) {
                    int m = rowbase + rt * 16 + mrow + e;
                    if (m < N_NODES) {
#pragma unroll
                        for (int ct = 0; ct < 4; ++ct)
                            cs[ct] += fmaxf(acc[rt][ct][e] + bcol[ct], 0.f);
                    }
                }
            }
        } else {
#pragma unroll
            for (int rt = 0; rt < 2; ++rt) {
#pragma unroll
                for (int e = 0; e < 4; ++e) {
                    int m = rowbase + rt * 16 + mrow + e;
                    if (m < N_NODES) {
#pragma unroll
                        for (int ct = 0; ct < 4; ++ct) {
                            float v = fmaxf(acc[rt][ct][e] + bcol[ct], 0.f);
                            Xout[(size_t)m * HIDDEN + col0 + ct * 16 + fr] = enc1(v);
                        }
                    }
                }
            }
        }
        __syncthreads();   // waves done reading buf; next-tile DMAs drained (covered by compute)
    }

    if constexpr (POOL) {
#pragma unroll
        for (int ct = 0; ct < 4; ++ct) {
            cs[ct] += __shfl_xor(cs[ct], 16);
            cs[ct] += __shfl_xor(cs[ct], 32);
        }
        if (lane < 16) {
#pragma unroll
            for (int ct = 0; ct < 4; ++ct)
                atomicAdd(&pooled[col0 + ct * 16 + lane], cs[ct]);
        }
    }
}

// ---------------- head MLP ----------------

__global__ void head_kernel(const float* __restrict__ pooled_sum, const float* __restrict__ cond,
                            const float* __restrict__ Wfc, const float* __restrict__ bfc,
                            const float* __restrict__ Wmean, const float* __restrict__ bmean,
                            const float* __restrict__ Wlogvar, const float* __restrict__ blogvar,
                            float* __restrict__ out) {
    __shared__ float v[HIDDEN + COND];
    __shared__ float h[LATENT];
    int t = threadIdx.x;
    if (t < HIDDEN) v[t] = pooled_sum[t] * (1.0f / N_NODES);
    if (t < COND) v[HIDDEN + t] = cond[t];
    __syncthreads();
    if (t < LATENT) {
        float s = bfc[t];
        for (int k = 0; k < HIDDEN + COND; ++k) s += v[k] * Wfc[k * LATENT + t];
        h[t] = fmaxf(s, 0.f);
    }
    __syncthreads();
    if (t < LATENT) {
        float s = bmean[t];
        for (int k = 0; k < LATENT; ++k) s += h[k] * Wmean[k * LATENT + t];
        out[t] = s;
    } else {
        int j = t - LATENT;
        float s = blogvar[j];
        for (int k = 0; k < LATENT; ++k) s += h[k] * Wlogvar[k * LATENT + j];
        out[LATENT + j] = s;
    }
}

// ---------------- launch ----------------

extern "C" void kernel_launch(void* const* d_in, const int* in_sizes, int n_in,
                              void* d_out, int out_size, void* d_ws, size_t ws_size,
                              hipStream_t stream) {
    const float* node_features = (const float*)d_in[0];
    const float* conditions    = (const float*)d_in[1];
    const int*   src           = (const int*)d_in[2];
    const int*   dst           = (const int*)d_in[3];
    const float* W1  = (const float*)d_in[4];
    const float* b1  = (const float*)d_in[5];
    const float* W2  = (const float*)d_in[6];
    const float* b2  = (const float*)d_in[7];
    const float* Wfc = (const float*)d_in[8];
    const float* bfc = (const float*)d_in[9];
    const float* Wmean   = (const float*)d_in[10];
    const float* bmean   = (const float*)d_in[11];
    const float* Wlogvar = (const float*)d_in[12];
    const float* blogvar = (const float*)d_in[13];
    float* out = (float*)d_out;

    size_t o = 0;
    auto alloc = [&](size_t bytes) {
        void* p = (char*)d_ws + o;
        o += (bytes + 255) & ~(size_t)255;
        return p;
    };
    int* offsets   = (int*)alloc((size_t)(N_NODES + 1) * 4);
    int* bcount    = (int*)alloc((size_t)NB * 4);
    int* bcursor2  = (int*)alloc((size_t)NB * 4);
    uint* pair_buf = (uint*)alloc((size_t)N_EDGES * 4);
    ushort* csr    = (ushort*)alloc((size_t)N_EDGES * 2);
    float* pooled  = (float*)alloc(HIDDEN * 4);
    ushort* Wst1   = (ushort*)alloc((size_t)HIDDEN * NODE_DIM * 2);
    ushort* Wst2   = (ushort*)alloc((size_t)HIDDEN * HIDDEN * 2);
    uchar* nf_fp8  = (uchar*)alloc((size_t)N_NODES * NODE_DIM);
    uchar* x1_fp8  = (uchar*)alloc((size_t)N_NODES * HIDDEN);
    // +64 rows pad: gemm staging reads past row 49999 (results masked)
    ushort* agg1   = (ushort*)alloc((size_t)(N_NODES + 64) * NODE_DIM * 2);
    ushort* agg2   = (ushort*)alloc((size_t)(N_NODES + 64) * HIDDEN * 2);

    prep_kernel<<<(PREP5 + 255) / 256, 256, 0, stream>>>(
        node_features, W1, W2, nf_fp8, Wst1, Wst2, pooled, bcount, bcursor2);

    bcount_kernel<<<P1_GRID, 256, 0, stream>>>(dst, bcount);
    bwrite_kernel<<<P1_GRID, 256, 0, stream>>>(src, dst, bcount, bcursor2, pair_buf);
    csrloc_kernel<<<NB, 256, 0, stream>>>(pair_buf, bcount, offsets, csr);

    const int AGG_GRID = (N_NODES * 64 + 255) / 256;
    const int G1_BLK = 512;   // 64KB LDS -> 2 blocks/CU
    const int G2_BLK = 256;   // 128KB LDS -> 1 block/CU

    agg_kernel<NODE_DIM><<<AGG_GRID, 256, 0, stream>>>(nf_fp8, offsets, csr, agg1);
    gemm_res_kernel<NODE_DIM, false><<<G1_BLK, 256, 0, stream>>>(agg1, Wst1, b1, x1_fp8, nullptr, G1_BLK);

    agg_kernel<HIDDEN><<<AGG_GRID, 256, 0, stream>>>(x1_fp8, offsets, csr, agg2);
    gemm_res_kernel<HIDDEN, true><<<G2_BLK, 256, 0, stream>>>(agg2, Wst2, b2, nullptr, pooled, G2_BLK);

    head_kernel<<<1, 256, 0, stream>>>(pooled, conditions, Wfc, bfc,
                                       Wmean, bmean, Wlogvar, blogvar, out);
}